// Round 6
// baseline (684.790 us; speedup 1.0000x reference)
//
#include <hip/hip_runtime.h>
#include <math.h>

typedef float  f4v __attribute__((ext_vector_type(4)));
typedef short  s8v __attribute__((ext_vector_type(8)));

__device__ __forceinline__ float sigm(float x) { return 1.f / (1.f + expf(-x)); }
__device__ __forceinline__ unsigned short f2bf(float f) {
    unsigned int u = __float_as_uint(f);
    return (unsigned short)((u + 0x7FFF + ((u >> 16) & 1)) >> 16);   // RTNE
}
__device__ __forceinline__ s8v pack8(float4 a, float4 b) {
    union { unsigned short u[8]; s8v v; } r;
    r.u[0] = f2bf(a.x); r.u[1] = f2bf(a.y); r.u[2] = f2bf(a.z); r.u[3] = f2bf(a.w);
    r.u[4] = f2bf(b.x); r.u[5] = f2bf(b.y); r.u[6] = f2bf(b.z); r.u[7] = f2bf(b.w);
    return r.v;
}
__device__ __forceinline__ s8v pack8s(float4 a, float4 b, float m) {
    union { unsigned short u[8]; s8v v; } r;
    r.u[0] = f2bf(a.x * m); r.u[1] = f2bf(a.y * m); r.u[2] = f2bf(a.z * m); r.u[3] = f2bf(a.w * m);
    r.u[4] = f2bf(b.x * m); r.u[5] = f2bf(b.y * m); r.u[6] = f2bf(b.z * m); r.u[7] = f2bf(b.w * m);
    return r.v;
}

// ---------------- prep: pack weights to bf16 [N][K] layouts ----------------
__global__ __launch_bounds__(256) void k_prep(const float* __restrict__ W2, const float* __restrict__ W3,
                                              const float* __restrict__ Wfc, const float* __restrict__ Wih,
                                              const float* __restrict__ W1,
                                              unsigned short* __restrict__ W2p, unsigned short* __restrict__ W3p,
                                              unsigned short* __restrict__ Wfcp, unsigned short* __restrict__ Wihp,
                                              unsigned short* __restrict__ W1p) {
    int i = blockIdx.x * 256 + threadIdx.x;
    if (i < 32768) {
        W2p[i] = f2bf(W2[i]);
    } else if (i < 98304) {
        int j = i - 32768;
        int co = j >> 10, r = j & 1023, ci = r >> 4, s = r & 15, ky = s >> 2, kx = s & 3;
        W3p[j] = (ky < 3 && kx < 3) ? f2bf(W3[((co * 64 + ci) * 3 + ky) * 3 + kx]) : (unsigned short)0;
    } else if (i < 1703936) {
        int j = i - 98304;
        Wfcp[j] = f2bf(Wfc[j]);
    } else if (i < 2228224) {
        int j = i - 1703936;
        int n = j >> 9, k = j & 511;
        Wihp[j] = f2bf(Wih[n * 517 + k]);
    } else if (i < 2234368) {
        int j = i - 2228224;
        W1p[j] = f2bf(W1[j] * (1.f / 255.f));
    }
}

// ---------------- conv1 (MFMA): M=409600, N=32, K=192; LDS-staged coalesced epilogue ----------------
__global__ __launch_bounds__(256) void k_conv1(const float* __restrict__ img,
                                               const unsigned short* __restrict__ Bw,
                                               const float* __restrict__ bias,
                                               unsigned short* __restrict__ out) {
    __shared__ unsigned short c1s[32][136];
    int lane = threadIdx.x & 63, w = threadIdx.x >> 6;
    int l15 = lane & 15, q = lane >> 4;
    int m0 = blockIdx.x * 128;
    int ma = m0 + w * 32 + l15, mb = ma + 16;
    int ia = ma / 400, pa = ma - ia * 400; int oya = pa / 20, oxa = pa - oya * 20;
    int ib = mb / 400, pb = mb - ib * 400; int oyb = pb / 20, oxb = pb - oyb * 20;
    const float* Aa = img + ia * 21168 + oya * 336 + oxa * 4;
    const float* Ab = img + ib * 21168 + oyb * 336 + oxb * 4;
    const unsigned short* Bp0 = Bw + l15 * 192 + q * 8;
    const unsigned short* Bp1 = Bw + (16 + l15) * 192 + q * 8;
    s8v bf0[6], bf1[6];
#pragma unroll
    for (int ks = 0; ks < 6; ++ks) {
        bf0[ks] = *(const s8v*)(Bp0 + ks * 32);
        bf1[ks] = *(const s8v*)(Bp1 + ks * 32);
    }
    f4v acc[4];
#pragma unroll
    for (int i = 0; i < 4; ++i) acc[i] = (f4v){0.f, 0.f, 0.f, 0.f};
#pragma unroll
    for (int ks = 0; ks < 6; ++ks) {
        int k0 = ks * 32 + q * 8;
        int c = k0 >> 6, ky = (k0 >> 3) & 7;
        const float* ra = Aa + c * 7056 + ky * 84;
        const float* rb = Ab + c * 7056 + ky * 84;
        float4 a0 = *(const float4*)(ra), a1 = *(const float4*)(ra + 4);
        float4 b0 = *(const float4*)(rb), b1 = *(const float4*)(rb + 4);
        s8v ua = pack8(a0, a1);
        s8v ub = pack8(b0, b1);
        acc[0] = __builtin_amdgcn_mfma_f32_16x16x32_bf16(ua, bf0[ks], acc[0], 0, 0, 0);
        acc[1] = __builtin_amdgcn_mfma_f32_16x16x32_bf16(ua, bf1[ks], acc[1], 0, 0, 0);
        acc[2] = __builtin_amdgcn_mfma_f32_16x16x32_bf16(ub, bf0[ks], acc[2], 0, 0, 0);
        acc[3] = __builtin_amdgcn_mfma_f32_16x16x32_bf16(ub, bf1[ks], acc[3], 0, 0, 0);
    }
#pragma unroll
    for (int nf = 0; nf < 2; ++nf) {
        int n = nf * 16 + l15;
        float b = bias[n];
#pragma unroll
        for (int mf = 0; mf < 2; ++mf) {
#pragma unroll
            for (int r = 0; r < 4; ++r) {
                int ml = w * 32 + mf * 16 + q * 4 + r;
                float v = acc[mf * 2 + nf][r] + b;
                c1s[n][ml] = f2bf(v > 0.f ? v : 0.f);
            }
        }
    }
    __syncthreads();
#pragma unroll
    for (int seg = 0; seg < 16; ++seg) {
        int flat = seg * 256 + threadIdx.x;
        int n = flat >> 7, ml = flat & 127;
        int m = m0 + ml;
        int im = m / 400, p = m - im * 400;
        out[(im * 32 + n) * 400 + p] = c1s[n][ml];
    }
}

// ---------------- conv2 (MFMA): M=82944, N=64, K=512; LDS-staged epilogue ----------------
__global__ __launch_bounds__(256) void k_conv2(const unsigned short* __restrict__ A,
                                               const unsigned short* __restrict__ Bw,
                                               const float* __restrict__ bias,
                                               unsigned short* __restrict__ out) {
    __shared__ unsigned short c2s[64][136];
    int lane = threadIdx.x & 63, w = threadIdx.x >> 6;
    int l15 = lane & 15, q = lane >> 4;
    int m0 = blockIdx.x * 128;
    int ma = m0 + w * 32 + l15, mb = ma + 16;
    int ia = ma / 81, pa = ma - ia * 81; int oya = pa / 9, oxa = pa - oya * 9;
    int ib = mb / 81, pb = mb - ib * 81; int oyb = pb / 9, oxb = pb - oyb * 9;
    const unsigned short* Aa = A + ia * 12800 + oya * 40 + oxa * 2 + (q & 1) * 40;
    const unsigned short* Ab = A + ib * 12800 + oyb * 40 + oxb * 2 + (q & 1) * 40;
    int ci0 = q >> 1;
    const unsigned short* B0 = Bw + (l15) * 512 + q * 8;
    const unsigned short* B1 = Bw + (16 + l15) * 512 + q * 8;
    const unsigned short* B2 = Bw + (32 + l15) * 512 + q * 8;
    const unsigned short* B3 = Bw + (48 + l15) * 512 + q * 8;
    f4v acc[8];
#pragma unroll
    for (int i = 0; i < 8; ++i) acc[i] = (f4v){0.f, 0.f, 0.f, 0.f};
    for (int c = 0; c < 16; ++c) {
        int ci = 2 * c + ci0;
        const unsigned short* pa_ = Aa + ci * 400;
        const unsigned short* pb_ = Ab + ci * 400;
        union { unsigned int u[4]; s8v v; } ua, ub;
        ua.u[0] = *(const unsigned int*)(pa_);      ua.u[1] = *(const unsigned int*)(pa_ + 2);
        ua.u[2] = *(const unsigned int*)(pa_ + 20); ua.u[3] = *(const unsigned int*)(pa_ + 22);
        ub.u[0] = *(const unsigned int*)(pb_);      ub.u[1] = *(const unsigned int*)(pb_ + 2);
        ub.u[2] = *(const unsigned int*)(pb_ + 20); ub.u[3] = *(const unsigned int*)(pb_ + 22);
        s8v b0 = *(const s8v*)B0, b1 = *(const s8v*)B1, b2 = *(const s8v*)B2, b3 = *(const s8v*)B3;
        B0 += 32; B1 += 32; B2 += 32; B3 += 32;
        acc[0] = __builtin_amdgcn_mfma_f32_16x16x32_bf16(ua.v, b0, acc[0], 0, 0, 0);
        acc[1] = __builtin_amdgcn_mfma_f32_16x16x32_bf16(ua.v, b1, acc[1], 0, 0, 0);
        acc[2] = __builtin_amdgcn_mfma_f32_16x16x32_bf16(ua.v, b2, acc[2], 0, 0, 0);
        acc[3] = __builtin_amdgcn_mfma_f32_16x16x32_bf16(ua.v, b3, acc[3], 0, 0, 0);
        acc[4] = __builtin_amdgcn_mfma_f32_16x16x32_bf16(ub.v, b0, acc[4], 0, 0, 0);
        acc[5] = __builtin_amdgcn_mfma_f32_16x16x32_bf16(ub.v, b1, acc[5], 0, 0, 0);
        acc[6] = __builtin_amdgcn_mfma_f32_16x16x32_bf16(ub.v, b2, acc[6], 0, 0, 0);
        acc[7] = __builtin_amdgcn_mfma_f32_16x16x32_bf16(ub.v, b3, acc[7], 0, 0, 0);
    }
#pragma unroll
    for (int nf = 0; nf < 4; ++nf) {
        int n = nf * 16 + l15;
        float b = bias[n];
#pragma unroll
        for (int mf = 0; mf < 2; ++mf) {
#pragma unroll
            for (int r = 0; r < 4; ++r) {
                int ml = w * 32 + mf * 16 + q * 4 + r;
                float v = acc[mf * 4 + nf][r] + b;
                c2s[n][ml] = f2bf(v > 0.f ? v : 0.f);
            }
        }
    }
    __syncthreads();
#pragma unroll
    for (int seg = 0; seg < 32; ++seg) {
        int flat = seg * 256 + threadIdx.x;
        int n = flat >> 7, ml = flat & 127;
        int m = m0 + ml;
        int im = m / 81, p = m - im * 81;
        out[im * 5184 + n * 81 + p] = c2s[n][ml];
    }
}

// ---------------- conv3 (MFMA): M=50176, N=64, K=64ci*16slots; LDS-staged epilogue ----------------
__global__ __launch_bounds__(256) void k_conv3(const unsigned short* __restrict__ A,
                                               const unsigned short* __restrict__ Bw,
                                               const float* __restrict__ bias,
                                               unsigned short* __restrict__ out) {
    __shared__ unsigned short c3s[64][136];
    int lane = threadIdx.x & 63, w = threadIdx.x >> 6;
    int l15 = lane & 15, q = lane >> 4;
    int m0 = blockIdx.x * 128;
    int ma = m0 + w * 32 + l15, mb = ma + 16;
    int ia = ma / 49, pa = ma - ia * 49; int oya = pa / 7, oxa = pa - oya * 7;
    int ib = mb / 49, pb = mb - ib * 49; int oyb = pb / 7, oxb = pb - oyb * 7;
    int ky0 = (q & 1) * 2;
    int r0off = ky0 * 9;
    int r1off = (ky0 + 1 > 2 ? 2 : ky0 + 1) * 9;
    int zr = q & 1;
    const unsigned short* Aa = A + ia * 5184 + oya * 9 + oxa;
    const unsigned short* Ab = A + ib * 5184 + oyb * 9 + oxb;
    int ci0 = q >> 1;
    const unsigned short* B0 = Bw + (l15) * 1024 + q * 8;
    const unsigned short* B1 = Bw + (16 + l15) * 1024 + q * 8;
    const unsigned short* B2 = Bw + (32 + l15) * 1024 + q * 8;
    const unsigned short* B3 = Bw + (48 + l15) * 1024 + q * 8;
    f4v acc[8];
#pragma unroll
    for (int i = 0; i < 8; ++i) acc[i] = (f4v){0.f, 0.f, 0.f, 0.f};
    for (int c = 0; c < 32; ++c) {
        int ci = 2 * c + ci0;
        const unsigned short* pa_ = Aa + ci * 81;
        const unsigned short* pb_ = Ab + ci * 81;
        s8v av, bv;
        av[0] = pa_[r0off]; av[1] = pa_[r0off + 1]; av[2] = pa_[r0off + 2]; av[3] = 0;
        av[4] = zr ? (short)0 : (short)pa_[r1off];
        av[5] = zr ? (short)0 : (short)pa_[r1off + 1];
        av[6] = zr ? (short)0 : (short)pa_[r1off + 2];
        av[7] = 0;
        bv[0] = pb_[r0off]; bv[1] = pb_[r0off + 1]; bv[2] = pb_[r0off + 2]; bv[3] = 0;
        bv[4] = zr ? (short)0 : (short)pb_[r1off];
        bv[5] = zr ? (short)0 : (short)pb_[r1off + 1];
        bv[6] = zr ? (short)0 : (short)pb_[r1off + 2];
        bv[7] = 0;
        s8v b0 = *(const s8v*)B0, b1 = *(const s8v*)B1, b2 = *(const s8v*)B2, b3 = *(const s8v*)B3;
        B0 += 32; B1 += 32; B2 += 32; B3 += 32;
        acc[0] = __builtin_amdgcn_mfma_f32_16x16x32_bf16(av, b0, acc[0], 0, 0, 0);
        acc[1] = __builtin_amdgcn_mfma_f32_16x16x32_bf16(av, b1, acc[1], 0, 0, 0);
        acc[2] = __builtin_amdgcn_mfma_f32_16x16x32_bf16(av, b2, acc[2], 0, 0, 0);
        acc[3] = __builtin_amdgcn_mfma_f32_16x16x32_bf16(av, b3, acc[3], 0, 0, 0);
        acc[4] = __builtin_amdgcn_mfma_f32_16x16x32_bf16(bv, b0, acc[4], 0, 0, 0);
        acc[5] = __builtin_amdgcn_mfma_f32_16x16x32_bf16(bv, b1, acc[5], 0, 0, 0);
        acc[6] = __builtin_amdgcn_mfma_f32_16x16x32_bf16(bv, b2, acc[6], 0, 0, 0);
        acc[7] = __builtin_amdgcn_mfma_f32_16x16x32_bf16(bv, b3, acc[7], 0, 0, 0);
    }
#pragma unroll
    for (int nf = 0; nf < 4; ++nf) {
        int n = nf * 16 + l15;
        float b = bias[n];
#pragma unroll
        for (int mf = 0; mf < 2; ++mf) {
#pragma unroll
            for (int r = 0; r < 4; ++r) {
                int ml = w * 32 + mf * 16 + q * 4 + r;
                float v = acc[mf * 4 + nf][r] + b;
                c3s[n][ml] = f2bf(v > 0.f ? v : 0.f);
            }
        }
    }
    __syncthreads();
#pragma unroll
    for (int seg = 0; seg < 32; ++seg) {
        int flat = seg * 256 + threadIdx.x;
        int n = flat >> 7, ml = flat & 127;
        int m = m0 + ml;
        int im = m / 49, p = m - im * 49;
        out[im * 3136 + n * 49 + p] = c3s[n][ml];
    }
}

// ---------------- FC (MFMA) ----------------
__global__ __launch_bounds__(256) void k_fc(const unsigned short* __restrict__ A,
                                            const unsigned short* __restrict__ Bw,
                                            const float* __restrict__ bias,
                                            unsigned short* __restrict__ out) {
    int lane = threadIdx.x & 63, w = threadIdx.x >> 6;
    int l15 = lane & 15, q = lane >> 4;
    int m0 = blockIdx.x * 32 + (w & 1) * 16;
    int n0 = blockIdx.y * 64 + (w >> 1) * 32;
    const unsigned short* Ap = A + (m0 + l15) * 3136 + q * 8;
    const unsigned short* B0 = Bw + (n0 + l15) * 3136 + q * 8;
    const unsigned short* B1 = B0 + 16 * 3136;
    f4v acc0 = (f4v){0.f, 0.f, 0.f, 0.f}, acc1 = (f4v){0.f, 0.f, 0.f, 0.f};
    for (int c = 0; c < 98; ++c) {
        s8v av = *(const s8v*)Ap;
        s8v b0 = *(const s8v*)B0;
        s8v b1 = *(const s8v*)B1;
        Ap += 32; B0 += 32; B1 += 32;
        acc0 = __builtin_amdgcn_mfma_f32_16x16x32_bf16(av, b0, acc0, 0, 0, 0);
        acc1 = __builtin_amdgcn_mfma_f32_16x16x32_bf16(av, b1, acc1, 0, 0, 0);
    }
    float bi0 = bias[n0 + l15], bi1 = bias[n0 + 16 + l15];
#pragma unroll
    for (int r = 0; r < 4; ++r) {
        int m = m0 + q * 4 + r;
        float v0 = acc0[r] + bi0; v0 = v0 > 0.f ? v0 : 0.f;
        float v1 = acc1[r] + bi1; v1 = v1 > 0.f ? v1 : 0.f;
        out[m * 512 + n0 + l15] = f2bf(v0);
        out[m * 512 + n0 + 16 + l15] = f2bf(v1);
    }
}

// ---------------- gx (MFMA) ----------------
__global__ __launch_bounds__(256) void k_gx(const unsigned short* __restrict__ A,
                                            const unsigned short* __restrict__ Bw,
                                            const float* __restrict__ Wih,
                                            const float* __restrict__ bih,
                                            const float* __restrict__ bhh,
                                            const int* __restrict__ act,
                                            float* __restrict__ out) {
    int lane = threadIdx.x & 63, w = threadIdx.x >> 6;
    int l15 = lane & 15, q = lane >> 4;
    int m0 = blockIdx.x * 32 + (w & 1) * 16;
    int n0 = blockIdx.y * 64 + (w >> 1) * 32;
    const unsigned short* Ap = A + (m0 + l15) * 512 + q * 8;
    const unsigned short* B0 = Bw + (n0 + l15) * 512 + q * 8;
    const unsigned short* B1 = B0 + 16 * 512;
    f4v acc0 = (f4v){0.f, 0.f, 0.f, 0.f}, acc1 = (f4v){0.f, 0.f, 0.f, 0.f};
    for (int c = 0; c < 16; ++c) {
        s8v av = *(const s8v*)Ap;
        s8v b0 = *(const s8v*)B0;
        s8v b1 = *(const s8v*)B1;
        Ap += 32; B0 += 32; B1 += 32;
        acc0 = __builtin_amdgcn_mfma_f32_16x16x32_bf16(av, b0, acc0, 0, 0, 0);
        acc1 = __builtin_amdgcn_mfma_f32_16x16x32_bf16(av, b1, acc1, 0, 0, 0);
    }
    int na = n0 + l15, nb = n0 + 16 + l15;
    float ca = bih[na] + bhh[na], cb_ = bih[nb] + bhh[nb];
#pragma unroll
    for (int r = 0; r < 4; ++r) {
        int m = m0 + q * 4 + r;
        int a = act[m];
        out[m * 1024 + na] = acc0[r] + Wih[na * 517 + 512 + a] + ca;
        out[m * 1024 + nb] = acc1[r] + Wih[nb * 517 + 512 + a] + cb_;
    }
}

// ---------------- fused LSTM: 16 persistent wgs; h exchanged via coherent (sc0 sc1) LLC ops ----------------
// Cross-wg data goes through relaxed agent-scope atomics (write-through to the coherent LLC;
// no buffer_wbl2/buffer_inv L2 maintenance). hm = double-buffered pre-masked bf16 h.
__global__ __launch_bounds__(256) void k_lstm_fused(const float* __restrict__ h0,
                                                    const float* __restrict__ c0,
                                                    const float* __restrict__ done,
                                                    const float* __restrict__ gx,
                                                    const float* __restrict__ Whh,
                                                    float* __restrict__ hs,
                                                    float* __restrict__ cb,
                                                    unsigned short* __restrict__ hm,
                                                    unsigned int* __restrict__ cnt) {
    int hu0 = blockIdx.x * 16;
    int lane = threadIdx.x & 63, g = threadIdx.x >> 6;
    int l15 = lane & 15, q = lane >> 4;
    __shared__ float gbuf[4][32][17];
    __shared__ float cst[32][16];

    const float* wrow = Whh + (g * 256 + hu0 + l15) * 256 + q * 8;
    s8v bfr[8];
#pragma unroll
    for (int ks = 0; ks < 8; ++ks) {
        float4 w0 = *(const float4*)(wrow + ks * 32);
        float4 w1 = *(const float4*)(wrow + ks * 32 + 4);
        bfr[ks] = pack8(w0, w1);
    }
    for (int i = threadIdx.x; i < 512; i += 256) {
        int b = i >> 4, u = i & 15;
        cst[b][u] = c0[b * 256 + hu0 + u];
    }
    __syncthreads();

    for (int t = 0; t < 32; ++t) {
        f4v acc0 = (f4v){0.f, 0.f, 0.f, 0.f}, acc1 = (f4v){0.f, 0.f, 0.f, 0.f};
        if (t == 0) {
            float mA = 1.f - done[l15];
            float mB = 1.f - done[16 + l15];
            const float* ha = h0 + l15 * 256 + q * 8;
            const float* hb = h0 + (16 + l15) * 256 + q * 8;
#pragma unroll
            for (int ks = 0; ks < 8; ++ks) {
                float4 x0 = *(const float4*)(ha + ks * 32);
                float4 x1 = *(const float4*)(ha + ks * 32 + 4);
                float4 y0 = *(const float4*)(hb + ks * 32);
                float4 y1 = *(const float4*)(hb + ks * 32 + 4);
                s8v av = pack8s(x0, x1, mA);
                s8v bv = pack8s(y0, y1, mB);
                acc0 = __builtin_amdgcn_mfma_f32_16x16x32_bf16(av, bfr[ks], acc0, 0, 0, 0);
                acc1 = __builtin_amdgcn_mfma_f32_16x16x32_bf16(bv, bfr[ks], acc1, 0, 0, 0);
            }
        } else {
            const unsigned int* hp = (const unsigned int*)(hm + ((t - 1) & 1) * 8192);
            int ba = l15 * 128 + q * 4;
            int bb = (16 + l15) * 128 + q * 4;
#pragma unroll
            for (int ks = 0; ks < 8; ++ks) {
                union { unsigned int u[4]; s8v v; } ua, ub;
                int off = ks * 16;
#pragma unroll
                for (int j = 0; j < 4; ++j)
                    ua.u[j] = __hip_atomic_load(hp + ba + off + j, __ATOMIC_RELAXED, __HIP_MEMORY_SCOPE_AGENT);
#pragma unroll
                for (int j = 0; j < 4; ++j)
                    ub.u[j] = __hip_atomic_load(hp + bb + off + j, __ATOMIC_RELAXED, __HIP_MEMORY_SCOPE_AGENT);
                acc0 = __builtin_amdgcn_mfma_f32_16x16x32_bf16(ua.v, bfr[ks], acc0, 0, 0, 0);
                acc1 = __builtin_amdgcn_mfma_f32_16x16x32_bf16(ub.v, bfr[ks], acc1, 0, 0, 0);
            }
        }
#pragma unroll
        for (int r = 0; r < 4; ++r) {
            gbuf[g][q * 4 + r][l15] = acc0[r];
            gbuf[g][16 + q * 4 + r][l15] = acc1[r];
        }
        __syncthreads();
        for (int i = threadIdx.x; i < 512; i += 256) {
            int b = i >> 4, u = i & 15;
            int n = hu0 + u;
            const float* gr = gx + (t * 32 + b) * 1024;
            float gi = gbuf[0][b][u] + gr[n];
            float gf = gbuf[1][b][u] + gr[256 + n];
            float gg = gbuf[2][b][u] + gr[512 + n];
            float go = gbuf[3][b][u] + gr[768 + n];
            float m = 1.f - done[t * 32 + b];
            float cm = cst[b][u] * m;
            float cn = sigm(gf) * cm + sigm(gi) * tanhf(gg);
            float hn = sigm(go) * tanhf(cn);
            cst[b][u] = cn;
            hs[t * 8192 + b * 256 + n] = hn;
            if (t < 31) {
                float m2 = 1.f - done[(t + 1) * 32 + b];
                unsigned short hb16 = f2bf(hn * m2);     // done in {0,1} -> exact
                __hip_atomic_store(hm + (t & 1) * 8192 + b * 256 + n, hb16,
                                   __ATOMIC_RELAXED, __HIP_MEMORY_SCOPE_AGENT);
            }
        }
        if (t < 31) {
            __builtin_amdgcn_s_waitcnt(0);       // hm/hs stores complete at the coherent point
            __syncthreads();
            if (threadIdx.x == 0) {
                __hip_atomic_fetch_add(cnt, 1u, __ATOMIC_RELAXED, __HIP_MEMORY_SCOPE_AGENT);
                unsigned int target = 16u * (unsigned int)(t + 1);
                while (__hip_atomic_load(cnt, __ATOMIC_RELAXED, __HIP_MEMORY_SCOPE_AGENT) < target)
                    __builtin_amdgcn_s_sleep(1);
            }
            __syncthreads();
            asm volatile("" ::: "memory");
        } else {
            __syncthreads();
        }
    }
    for (int i = threadIdx.x; i < 512; i += 256) {
        int b = i >> 4, u = i & 15;
        cb[b * 256 + hu0 + u] = cst[b][u];
    }
}

// ---------------- heads (fp32, unchanged) ----------------
__global__ __launch_bounds__(256) void k_heads(const float* __restrict__ hs,
                                               const float* __restrict__ cb,
                                               const float* __restrict__ Wp1, const float* __restrict__ bp1,
                                               const float* __restrict__ Wp2, const float* __restrict__ bp2,
                                               const float* __restrict__ Wv1, const float* __restrict__ bv1,
                                               const float* __restrict__ Wv2, const float* __restrict__ bv2,
                                               float* __restrict__ out) {
    int lane = threadIdx.x & 63;
    int m = blockIdx.x * 4 + (threadIdx.x >> 6);   // 0..1023
    const float4* hv = (const float4*)(hs + m * 256);
    const float4* wp = (const float4*)(Wp1 + lane * 256);
    const float4* wq = (const float4*)(Wv1 + lane * 256);
    float ap = 0.f, av = 0.f;
#pragma unroll 8
    for (int k = 0; k < 64; ++k) {
        float4 h4 = hv[k];
        float4 p4 = wp[k];
        float4 q4 = wq[k];
        ap += h4.x * p4.x + h4.y * p4.y + h4.z * p4.z + h4.w * p4.w;
        av += h4.x * q4.x + h4.y * q4.y + h4.z * q4.z + h4.w * q4.w;
    }
    float hp = tanhf(ap + bp1[lane]);
    float hq = tanhf(av + bv1[lane]);
#pragma unroll
    for (int j = 0; j < 5; ++j) {
        float s = hp * Wp2[j * 64 + lane];
        s += __shfl_xor(s, 1); s += __shfl_xor(s, 2); s += __shfl_xor(s, 4);
        s += __shfl_xor(s, 8); s += __shfl_xor(s, 16); s += __shfl_xor(s, 32);
        if (lane == 0) out[m * 5 + j] = s + bp2[j];
    }
    float s = hq * Wv2[lane];
    s += __shfl_xor(s, 1); s += __shfl_xor(s, 2); s += __shfl_xor(s, 4);
    s += __shfl_xor(s, 8); s += __shfl_xor(s, 16); s += __shfl_xor(s, 32);
    if (lane == 0) out[5120 + m] = s + bv2[0];

    int g = blockIdx.x * 256 + threadIdx.x;
    if (g < 8192) {
        out[6144 + g] = hs[31 * 8192 + g];          // hT
        out[6144 + 8192 + g] = cb[g];               // cT
    }
}

extern "C" void kernel_launch(void* const* d_in, const int* in_sizes, int n_in,
                              void* d_out, int out_size, void* d_ws, size_t ws_size,
                              hipStream_t stream) {
    const float* image = (const float*)d_in[0];
    const int*   act   = (const int*)d_in[1];
    const float* done  = (const float*)d_in[2];
    const float* h0    = (const float*)d_in[3];
    const float* c0    = (const float*)d_in[4];
    const float* W1    = (const float*)d_in[5];
    const float* b1    = (const float*)d_in[6];
    const float* W2    = (const float*)d_in[7];
    const float* b2    = (const float*)d_in[8];
    const float* W3    = (const float*)d_in[9];
    const float* b3    = (const float*)d_in[10];
    const float* Wfc   = (const float*)d_in[11];
    const float* bfc   = (const float*)d_in[12];
    const float* Wih   = (const float*)d_in[13];
    const float* Whh   = (const float*)d_in[14];
    const float* bih   = (const float*)d_in[15];
    const float* bhh   = (const float*)d_in[16];
    const float* Wp1   = (const float*)d_in[17];
    const float* bp1   = (const float*)d_in[18];
    const float* Wp2   = (const float*)d_in[19];
    const float* bp2   = (const float*)d_in[20];
    const float* Wv1   = (const float*)d_in[21];
    const float* bv1   = (const float*)d_in[22];
    const float* Wv2   = (const float*)d_in[23];
    const float* bv2   = (const float*)d_in[24];
    float* out = (float*)d_out;
    char* base = (char*)d_ws;

    // ---- workspace layout (bytes) ----
    unsigned short* a1   = (unsigned short*)(base);             // 26,214,400
    unsigned short* a2   = (unsigned short*)(base + 26214432);  // 10,616,832
    unsigned short* W2p  = (unsigned short*)(base + 36831328);
    unsigned short* W3p  = W2p + 32768;
    unsigned short* Wfcp = W2p + 98304;
    unsigned short* Wihp = W2p + 1703936;
    unsigned short* W1p  = (unsigned short*)(base + 41287776);  // 12,288
    unsigned int*   cnt  = (unsigned int*)(base + 41300064);    // 4
    unsigned short* a3   = (unsigned short*)(base);             // overlays dead a1
    unsigned short* feat = (unsigned short*)(base + 6422528);
    float* gx = (float*)(base + 7471104);
    float* hs = (float*)(base + 11665408);
    float* cb = (float*)(base + 12713984);
    unsigned short* hm = (unsigned short*)(base + 12746752);    // 2 x 8192 bf16 = 32,768 B

    k_prep<<<8728, 256, 0, stream>>>(W2, W3, Wfc, Wih, W1, W2p, W3p, Wfcp, Wihp, W1p);
    k_conv1<<<3200, 256, 0, stream>>>(image, W1p, b1, a1);
    k_conv2<<<648, 256, 0, stream>>>(a1, W2p, b2, a2);
    k_conv3<<<392, 256, 0, stream>>>(a2, W3p, b3, a3);
    k_fc<<<dim3(32, 8), 256, 0, stream>>>(a3, Wfcp, bfc, feat);
    k_gx<<<dim3(32, 16), 256, 0, stream>>>(feat, Wihp, Wih, bih, bhh, act, gx);
    hipMemsetAsync(cnt, 0, 4, stream);
    k_lstm_fused<<<16, 256, 0, stream>>>(h0, c0, done, gx, Whh, hs, cb, hm, cnt);
    k_heads<<<256, 256, 0, stream>>>(hs, cb, Wp1, bp1, Wp2, bp2, Wv1, bv1, Wv2, bv2, out);
}

// Round 7
// 530.070 us; speedup vs baseline: 1.2919x; 1.2919x over previous
//
#include <hip/hip_runtime.h>
#include <math.h>

typedef float  f4v __attribute__((ext_vector_type(4)));
typedef short  s8v __attribute__((ext_vector_type(8)));

__device__ __forceinline__ float sigm(float x) { return 1.f / (1.f + expf(-x)); }
__device__ __forceinline__ unsigned short f2bf(float f) {
    unsigned int u = __float_as_uint(f);
    return (unsigned short)((u + 0x7FFF + ((u >> 16) & 1)) >> 16);   // RTNE
}
__device__ __forceinline__ s8v pack8(float4 a, float4 b) {
    union { unsigned short u[8]; s8v v; } r;
    r.u[0] = f2bf(a.x); r.u[1] = f2bf(a.y); r.u[2] = f2bf(a.z); r.u[3] = f2bf(a.w);
    r.u[4] = f2bf(b.x); r.u[5] = f2bf(b.y); r.u[6] = f2bf(b.z); r.u[7] = f2bf(b.w);
    return r.v;
}
__device__ __forceinline__ s8v pack8s(float4 a, float4 b, float m) {
    union { unsigned short u[8]; s8v v; } r;
    r.u[0] = f2bf(a.x * m); r.u[1] = f2bf(a.y * m); r.u[2] = f2bf(a.z * m); r.u[3] = f2bf(a.w * m);
    r.u[4] = f2bf(b.x * m); r.u[5] = f2bf(b.y * m); r.u[6] = f2bf(b.z * m); r.u[7] = f2bf(b.w * m);
    return r.v;
}

// ---------------- prep: pack weights to bf16 [N][K] layouts ----------------
__global__ __launch_bounds__(256) void k_prep(const float* __restrict__ W2, const float* __restrict__ W3,
                                              const float* __restrict__ Wfc, const float* __restrict__ Wih,
                                              const float* __restrict__ W1, const float* __restrict__ Whh,
                                              unsigned short* __restrict__ W2p, unsigned short* __restrict__ W3p,
                                              unsigned short* __restrict__ Wfcp, unsigned short* __restrict__ Wihp,
                                              unsigned short* __restrict__ W1p, unsigned short* __restrict__ Whhp) {
    int i = blockIdx.x * 256 + threadIdx.x;
    if (i < 32768) {
        W2p[i] = f2bf(W2[i]);
    } else if (i < 98304) {
        int j = i - 32768;
        int co = j >> 10, r = j & 1023, ci = r >> 4, s = r & 15, ky = s >> 2, kx = s & 3;
        W3p[j] = (ky < 3 && kx < 3) ? f2bf(W3[((co * 64 + ci) * 3 + ky) * 3 + kx]) : (unsigned short)0;
    } else if (i < 1703936) {
        int j = i - 98304;
        Wfcp[j] = f2bf(Wfc[j]);
    } else if (i < 2228224) {
        int j = i - 1703936;
        int n = j >> 9, k = j & 511;
        Wihp[j] = f2bf(Wih[n * 517 + k]);
    } else if (i < 2234368) {
        int j = i - 2228224;
        W1p[j] = f2bf(W1[j] * (1.f / 255.f));
    } else if (i < 2496512) {
        int j = i - 2234368;
        Whhp[j] = f2bf(Whh[j]);                    // [1024][256] natural
    }
}

// ---------------- conv1 (MFMA): M=409600, N=32, K=192; LDS-staged coalesced epilogue ----------------
__global__ __launch_bounds__(256) void k_conv1(const float* __restrict__ img,
                                               const unsigned short* __restrict__ Bw,
                                               const float* __restrict__ bias,
                                               unsigned short* __restrict__ out) {
    __shared__ unsigned short c1s[32][136];
    int lane = threadIdx.x & 63, w = threadIdx.x >> 6;
    int l15 = lane & 15, q = lane >> 4;
    int m0 = blockIdx.x * 128;
    int ma = m0 + w * 32 + l15, mb = ma + 16;
    int ia = ma / 400, pa = ma - ia * 400; int oya = pa / 20, oxa = pa - oya * 20;
    int ib = mb / 400, pb = mb - ib * 400; int oyb = pb / 20, oxb = pb - oyb * 20;
    const float* Aa = img + ia * 21168 + oya * 336 + oxa * 4;
    const float* Ab = img + ib * 21168 + oyb * 336 + oxb * 4;
    const unsigned short* Bp0 = Bw + l15 * 192 + q * 8;
    const unsigned short* Bp1 = Bw + (16 + l15) * 192 + q * 8;
    s8v bf0[6], bf1[6];
#pragma unroll
    for (int ks = 0; ks < 6; ++ks) {
        bf0[ks] = *(const s8v*)(Bp0 + ks * 32);
        bf1[ks] = *(const s8v*)(Bp1 + ks * 32);
    }
    f4v acc[4];
#pragma unroll
    for (int i = 0; i < 4; ++i) acc[i] = (f4v){0.f, 0.f, 0.f, 0.f};
#pragma unroll
    for (int ks = 0; ks < 6; ++ks) {
        int k0 = ks * 32 + q * 8;
        int c = k0 >> 6, ky = (k0 >> 3) & 7;
        const float* ra = Aa + c * 7056 + ky * 84;
        const float* rb = Ab + c * 7056 + ky * 84;
        float4 a0 = *(const float4*)(ra), a1 = *(const float4*)(ra + 4);
        float4 b0 = *(const float4*)(rb), b1 = *(const float4*)(rb + 4);
        s8v ua = pack8(a0, a1);
        s8v ub = pack8(b0, b1);
        acc[0] = __builtin_amdgcn_mfma_f32_16x16x32_bf16(ua, bf0[ks], acc[0], 0, 0, 0);
        acc[1] = __builtin_amdgcn_mfma_f32_16x16x32_bf16(ua, bf1[ks], acc[1], 0, 0, 0);
        acc[2] = __builtin_amdgcn_mfma_f32_16x16x32_bf16(ub, bf0[ks], acc[2], 0, 0, 0);
        acc[3] = __builtin_amdgcn_mfma_f32_16x16x32_bf16(ub, bf1[ks], acc[3], 0, 0, 0);
    }
#pragma unroll
    for (int nf = 0; nf < 2; ++nf) {
        int n = nf * 16 + l15;
        float b = bias[n];
#pragma unroll
        for (int mf = 0; mf < 2; ++mf) {
#pragma unroll
            for (int r = 0; r < 4; ++r) {
                int ml = w * 32 + mf * 16 + q * 4 + r;
                float v = acc[mf * 2 + nf][r] + b;
                c1s[n][ml] = f2bf(v > 0.f ? v : 0.f);
            }
        }
    }
    __syncthreads();
#pragma unroll
    for (int seg = 0; seg < 16; ++seg) {
        int flat = seg * 256 + threadIdx.x;
        int n = flat >> 7, ml = flat & 127;
        int m = m0 + ml;
        int im = m / 400, p = m - im * 400;
        out[(im * 32 + n) * 400 + p] = c1s[n][ml];
    }
}

// ---------------- conv2 (MFMA): M=82944, N=64, K=512; LDS-staged epilogue ----------------
__global__ __launch_bounds__(256) void k_conv2(const unsigned short* __restrict__ A,
                                               const unsigned short* __restrict__ Bw,
                                               const float* __restrict__ bias,
                                               unsigned short* __restrict__ out) {
    __shared__ unsigned short c2s[64][136];
    int lane = threadIdx.x & 63, w = threadIdx.x >> 6;
    int l15 = lane & 15, q = lane >> 4;
    int m0 = blockIdx.x * 128;
    int ma = m0 + w * 32 + l15, mb = ma + 16;
    int ia = ma / 81, pa = ma - ia * 81; int oya = pa / 9, oxa = pa - oya * 9;
    int ib = mb / 81, pb = mb - ib * 81; int oyb = pb / 9, oxb = pb - oyb * 9;
    const unsigned short* Aa = A + ia * 12800 + oya * 40 + oxa * 2 + (q & 1) * 40;
    const unsigned short* Ab = A + ib * 12800 + oyb * 40 + oxb * 2 + (q & 1) * 40;
    int ci0 = q >> 1;
    const unsigned short* B0 = Bw + (l15) * 512 + q * 8;
    const unsigned short* B1 = Bw + (16 + l15) * 512 + q * 8;
    const unsigned short* B2 = Bw + (32 + l15) * 512 + q * 8;
    const unsigned short* B3 = Bw + (48 + l15) * 512 + q * 8;
    f4v acc[8];
#pragma unroll
    for (int i = 0; i < 8; ++i) acc[i] = (f4v){0.f, 0.f, 0.f, 0.f};
    for (int c = 0; c < 16; ++c) {
        int ci = 2 * c + ci0;
        const unsigned short* pa_ = Aa + ci * 400;
        const unsigned short* pb_ = Ab + ci * 400;
        union { unsigned int u[4]; s8v v; } ua, ub;
        ua.u[0] = *(const unsigned int*)(pa_);      ua.u[1] = *(const unsigned int*)(pa_ + 2);
        ua.u[2] = *(const unsigned int*)(pa_ + 20); ua.u[3] = *(const unsigned int*)(pa_ + 22);
        ub.u[0] = *(const unsigned int*)(pb_);      ub.u[1] = *(const unsigned int*)(pb_ + 2);
        ub.u[2] = *(const unsigned int*)(pb_ + 20); ub.u[3] = *(const unsigned int*)(pb_ + 22);
        s8v b0 = *(const s8v*)B0, b1 = *(const s8v*)B1, b2 = *(const s8v*)B2, b3 = *(const s8v*)B3;
        B0 += 32; B1 += 32; B2 += 32; B3 += 32;
        acc[0] = __builtin_amdgcn_mfma_f32_16x16x32_bf16(ua.v, b0, acc[0], 0, 0, 0);
        acc[1] = __builtin_amdgcn_mfma_f32_16x16x32_bf16(ua.v, b1, acc[1], 0, 0, 0);
        acc[2] = __builtin_amdgcn_mfma_f32_16x16x32_bf16(ua.v, b2, acc[2], 0, 0, 0);
        acc[3] = __builtin_amdgcn_mfma_f32_16x16x32_bf16(ua.v, b3, acc[3], 0, 0, 0);
        acc[4] = __builtin_amdgcn_mfma_f32_16x16x32_bf16(ub.v, b0, acc[4], 0, 0, 0);
        acc[5] = __builtin_amdgcn_mfma_f32_16x16x32_bf16(ub.v, b1, acc[5], 0, 0, 0);
        acc[6] = __builtin_amdgcn_mfma_f32_16x16x32_bf16(ub.v, b2, acc[6], 0, 0, 0);
        acc[7] = __builtin_amdgcn_mfma_f32_16x16x32_bf16(ub.v, b3, acc[7], 0, 0, 0);
    }
#pragma unroll
    for (int nf = 0; nf < 4; ++nf) {
        int n = nf * 16 + l15;
        float b = bias[n];
#pragma unroll
        for (int mf = 0; mf < 2; ++mf) {
#pragma unroll
            for (int r = 0; r < 4; ++r) {
                int ml = w * 32 + mf * 16 + q * 4 + r;
                float v = acc[mf * 4 + nf][r] + b;
                c2s[n][ml] = f2bf(v > 0.f ? v : 0.f);
            }
        }
    }
    __syncthreads();
#pragma unroll
    for (int seg = 0; seg < 32; ++seg) {
        int flat = seg * 256 + threadIdx.x;
        int n = flat >> 7, ml = flat & 127;
        int m = m0 + ml;
        int im = m / 81, p = m - im * 81;
        out[im * 5184 + n * 81 + p] = c2s[n][ml];
    }
}

// ---------------- conv3 (MFMA): M=50176, N=64, K=64ci*16slots; LDS-staged epilogue ----------------
__global__ __launch_bounds__(256) void k_conv3(const unsigned short* __restrict__ A,
                                               const unsigned short* __restrict__ Bw,
                                               const float* __restrict__ bias,
                                               unsigned short* __restrict__ out) {
    __shared__ unsigned short c3s[64][136];
    int lane = threadIdx.x & 63, w = threadIdx.x >> 6;
    int l15 = lane & 15, q = lane >> 4;
    int m0 = blockIdx.x * 128;
    int ma = m0 + w * 32 + l15, mb = ma + 16;
    int ia = ma / 49, pa = ma - ia * 49; int oya = pa / 7, oxa = pa - oya * 7;
    int ib = mb / 49, pb = mb - ib * 49; int oyb = pb / 7, oxb = pb - oyb * 7;
    int ky0 = (q & 1) * 2;
    int r0off = ky0 * 9;
    int r1off = (ky0 + 1 > 2 ? 2 : ky0 + 1) * 9;
    int zr = q & 1;
    const unsigned short* Aa = A + ia * 5184 + oya * 9 + oxa;
    const unsigned short* Ab = A + ib * 5184 + oyb * 9 + oxb;
    int ci0 = q >> 1;
    const unsigned short* B0 = Bw + (l15) * 1024 + q * 8;
    const unsigned short* B1 = Bw + (16 + l15) * 1024 + q * 8;
    const unsigned short* B2 = Bw + (32 + l15) * 1024 + q * 8;
    const unsigned short* B3 = Bw + (48 + l15) * 1024 + q * 8;
    f4v acc[8];
#pragma unroll
    for (int i = 0; i < 8; ++i) acc[i] = (f4v){0.f, 0.f, 0.f, 0.f};
    for (int c = 0; c < 32; ++c) {
        int ci = 2 * c + ci0;
        const unsigned short* pa_ = Aa + ci * 81;
        const unsigned short* pb_ = Ab + ci * 81;
        s8v av, bv;
        av[0] = pa_[r0off]; av[1] = pa_[r0off + 1]; av[2] = pa_[r0off + 2]; av[3] = 0;
        av[4] = zr ? (short)0 : (short)pa_[r1off];
        av[5] = zr ? (short)0 : (short)pa_[r1off + 1];
        av[6] = zr ? (short)0 : (short)pa_[r1off + 2];
        av[7] = 0;
        bv[0] = pb_[r0off]; bv[1] = pb_[r0off + 1]; bv[2] = pb_[r0off + 2]; bv[3] = 0;
        bv[4] = zr ? (short)0 : (short)pb_[r1off];
        bv[5] = zr ? (short)0 : (short)pb_[r1off + 1];
        bv[6] = zr ? (short)0 : (short)pb_[r1off + 2];
        bv[7] = 0;
        s8v b0 = *(const s8v*)B0, b1 = *(const s8v*)B1, b2 = *(const s8v*)B2, b3 = *(const s8v*)B3;
        B0 += 32; B1 += 32; B2 += 32; B3 += 32;
        acc[0] = __builtin_amdgcn_mfma_f32_16x16x32_bf16(av, b0, acc[0], 0, 0, 0);
        acc[1] = __builtin_amdgcn_mfma_f32_16x16x32_bf16(av, b1, acc[1], 0, 0, 0);
        acc[2] = __builtin_amdgcn_mfma_f32_16x16x32_bf16(av, b2, acc[2], 0, 0, 0);
        acc[3] = __builtin_amdgcn_mfma_f32_16x16x32_bf16(av, b3, acc[3], 0, 0, 0);
        acc[4] = __builtin_amdgcn_mfma_f32_16x16x32_bf16(bv, b0, acc[4], 0, 0, 0);
        acc[5] = __builtin_amdgcn_mfma_f32_16x16x32_bf16(bv, b1, acc[5], 0, 0, 0);
        acc[6] = __builtin_amdgcn_mfma_f32_16x16x32_bf16(bv, b2, acc[6], 0, 0, 0);
        acc[7] = __builtin_amdgcn_mfma_f32_16x16x32_bf16(bv, b3, acc[7], 0, 0, 0);
    }
#pragma unroll
    for (int nf = 0; nf < 4; ++nf) {
        int n = nf * 16 + l15;
        float b = bias[n];
#pragma unroll
        for (int mf = 0; mf < 2; ++mf) {
#pragma unroll
            for (int r = 0; r < 4; ++r) {
                int ml = w * 32 + mf * 16 + q * 4 + r;
                float v = acc[mf * 4 + nf][r] + b;
                c3s[n][ml] = f2bf(v > 0.f ? v : 0.f);
            }
        }
    }
    __syncthreads();
#pragma unroll
    for (int seg = 0; seg < 32; ++seg) {
        int flat = seg * 256 + threadIdx.x;
        int n = flat >> 7, ml = flat & 127;
        int m = m0 + ml;
        int im = m / 49, p = m - im * 49;
        out[im * 3136 + n * 49 + p] = c3s[n][ml];
    }
}

// ---------------- FC (MFMA) ----------------
__global__ __launch_bounds__(256) void k_fc(const unsigned short* __restrict__ A,
                                            const unsigned short* __restrict__ Bw,
                                            const float* __restrict__ bias,
                                            unsigned short* __restrict__ out) {
    int lane = threadIdx.x & 63, w = threadIdx.x >> 6;
    int l15 = lane & 15, q = lane >> 4;
    int m0 = blockIdx.x * 32 + (w & 1) * 16;
    int n0 = blockIdx.y * 64 + (w >> 1) * 32;
    const unsigned short* Ap = A + (m0 + l15) * 3136 + q * 8;
    const unsigned short* B0 = Bw + (n0 + l15) * 3136 + q * 8;
    const unsigned short* B1 = B0 + 16 * 3136;
    f4v acc0 = (f4v){0.f, 0.f, 0.f, 0.f}, acc1 = (f4v){0.f, 0.f, 0.f, 0.f};
    for (int c = 0; c < 98; ++c) {
        s8v av = *(const s8v*)Ap;
        s8v b0 = *(const s8v*)B0;
        s8v b1 = *(const s8v*)B1;
        Ap += 32; B0 += 32; B1 += 32;
        acc0 = __builtin_amdgcn_mfma_f32_16x16x32_bf16(av, b0, acc0, 0, 0, 0);
        acc1 = __builtin_amdgcn_mfma_f32_16x16x32_bf16(av, b1, acc1, 0, 0, 0);
    }
    float bi0 = bias[n0 + l15], bi1 = bias[n0 + 16 + l15];
#pragma unroll
    for (int r = 0; r < 4; ++r) {
        int m = m0 + q * 4 + r;
        float v0 = acc0[r] + bi0; v0 = v0 > 0.f ? v0 : 0.f;
        float v1 = acc1[r] + bi1; v1 = v1 > 0.f ? v1 : 0.f;
        out[m * 512 + n0 + l15] = f2bf(v0);
        out[m * 512 + n0 + 16 + l15] = f2bf(v1);
    }
}

// ---------------- gx (MFMA) ----------------
__global__ __launch_bounds__(256) void k_gx(const unsigned short* __restrict__ A,
                                            const unsigned short* __restrict__ Bw,
                                            const float* __restrict__ Wih,
                                            const float* __restrict__ bih,
                                            const float* __restrict__ bhh,
                                            const int* __restrict__ act,
                                            float* __restrict__ out) {
    int lane = threadIdx.x & 63, w = threadIdx.x >> 6;
    int l15 = lane & 15, q = lane >> 4;
    int m0 = blockIdx.x * 32 + (w & 1) * 16;
    int n0 = blockIdx.y * 64 + (w >> 1) * 32;
    const unsigned short* Ap = A + (m0 + l15) * 512 + q * 8;
    const unsigned short* B0 = Bw + (n0 + l15) * 512 + q * 8;
    const unsigned short* B1 = B0 + 16 * 512;
    f4v acc0 = (f4v){0.f, 0.f, 0.f, 0.f}, acc1 = (f4v){0.f, 0.f, 0.f, 0.f};
    for (int c = 0; c < 16; ++c) {
        s8v av = *(const s8v*)Ap;
        s8v b0 = *(const s8v*)B0;
        s8v b1 = *(const s8v*)B1;
        Ap += 32; B0 += 32; B1 += 32;
        acc0 = __builtin_amdgcn_mfma_f32_16x16x32_bf16(av, b0, acc0, 0, 0, 0);
        acc1 = __builtin_amdgcn_mfma_f32_16x16x32_bf16(av, b1, acc1, 0, 0, 0);
    }
    int na = n0 + l15, nb = n0 + 16 + l15;
    float ca = bih[na] + bhh[na], cb_ = bih[nb] + bhh[nb];
#pragma unroll
    for (int r = 0; r < 4; ++r) {
        int m = m0 + q * 4 + r;
        int a = act[m];
        out[m * 1024 + na] = acc0[r] + Wih[na * 517 + 512 + a] + ca;
        out[m * 1024 + nb] = acc1[r] + Wih[nb * 517 + 512 + a] + cb_;
    }
}

// ---------------- LSTM init: build masked A-frag h buffer for t=0; copy c0 -> cb ----------------
// hma unit layout: unit = (mt*8+ks)*64 + lane holds bf16 h[b=mt*16+(lane&15)][k=ks*32+(lane>>4)*8 ..+8]
__global__ __launch_bounds__(256) void k_lstm_init(const float* __restrict__ h0,
                                                   const float* __restrict__ c0,
                                                   const float* __restrict__ done,
                                                   unsigned short* __restrict__ hma,
                                                   float* __restrict__ cb) {
    int tid = blockIdx.x * 256 + threadIdx.x;       // 0..4095
    int lane = tid & 63, ks = (tid >> 6) & 7, mt = tid >> 9;
    int l15 = lane & 15, q = lane >> 4;
    int b = mt * 16 + l15;
    int k0 = ks * 32 + q * 8;
    float m = 1.f - done[b];
    const float* hp = h0 + b * 256 + k0;
    float4 x0 = *(const float4*)(hp);
    float4 x1 = *(const float4*)(hp + 4);
    *(s8v*)(hma + tid * 8) = pack8s(x0, x1, m);
    cb[tid * 2] = c0[tid * 2];
    cb[tid * 2 + 1] = c0[tid * 2 + 1];
}

// ---------------- one LSTM step (MFMA, 16 wgs): plain loads/stores, kernel boundary = barrier ----
// wg owns 16 hidden units (u0 = blockIdx.x*16); wave g = gate. h in A-frag layout (hma double buffer),
// pre-masked with done[t]. c in global cb. Writes hs[t] (fp32) and hma_out (bf16, masked for t+1).
__global__ __launch_bounds__(256) void k_lstm_step(int t,
                                                   const unsigned short* __restrict__ hma_in,
                                                   unsigned short* __restrict__ hma_out,
                                                   const float* __restrict__ done,
                                                   const float* __restrict__ gx,
                                                   const unsigned short* __restrict__ Whhp,
                                                   float* __restrict__ cbuf,
                                                   float* __restrict__ hs) {
    int u0 = blockIdx.x * 16;
    int lane = threadIdx.x & 63, g = threadIdx.x >> 6;
    int l15 = lane & 15, q = lane >> 4;
    __shared__ float gbuf[4][32][17];

    const unsigned short* brow = Whhp + (g * 256 + u0 + l15) * 256 + q * 8;
    const s8v* ha = (const s8v*)hma_in;
    f4v acc0 = (f4v){0.f, 0.f, 0.f, 0.f}, acc1 = (f4v){0.f, 0.f, 0.f, 0.f};
#pragma unroll
    for (int ks = 0; ks < 8; ++ks) {
        s8v bf = *(const s8v*)(brow + ks * 32);
        s8v a0 = ha[ks * 64 + lane];
        s8v a1 = ha[(8 + ks) * 64 + lane];
        acc0 = __builtin_amdgcn_mfma_f32_16x16x32_bf16(a0, bf, acc0, 0, 0, 0);
        acc1 = __builtin_amdgcn_mfma_f32_16x16x32_bf16(a1, bf, acc1, 0, 0, 0);
    }
#pragma unroll
    for (int r = 0; r < 4; ++r) {
        gbuf[g][q * 4 + r][l15] = acc0[r];
        gbuf[g][16 + q * 4 + r][l15] = acc1[r];
    }
    __syncthreads();
    for (int i = threadIdx.x; i < 512; i += 256) {
        int b = i >> 4, u = i & 15;
        int n = u0 + u;
        const float* gr = gx + (t * 32 + b) * 1024;
        float gi = gbuf[0][b][u] + gr[n];
        float gf = gbuf[1][b][u] + gr[256 + n];
        float gg = gbuf[2][b][u] + gr[512 + n];
        float go = gbuf[3][b][u] + gr[768 + n];
        float m = 1.f - done[t * 32 + b];
        float cm = cbuf[b * 256 + n] * m;
        float cn = sigm(gf) * cm + sigm(gi) * tanhf(gg);
        float hn = sigm(go) * tanhf(cn);
        cbuf[b * 256 + n] = cn;
        hs[t * 8192 + b * 256 + n] = hn;
        if (t < 31) {
            float m2 = 1.f - done[(t + 1) * 32 + b];
            // scatter into A-frag layout: mt=b>>4, l15'=b&15, ks=n>>5, q'=(n>>3)&3, j=n&7
            int ofs = (((b >> 4) * 8 + (n >> 5)) * 64 + ((n >> 3) & 3) * 16 + (b & 15)) * 8 + (n & 7);
            hma_out[ofs] = f2bf(hn * m2);            // done in {0,1} -> exact
        }
    }
}

// ---------------- heads (fp32, unchanged) ----------------
__global__ __launch_bounds__(256) void k_heads(const float* __restrict__ hs,
                                               const float* __restrict__ cb,
                                               const float* __restrict__ Wp1, const float* __restrict__ bp1,
                                               const float* __restrict__ Wp2, const float* __restrict__ bp2,
                                               const float* __restrict__ Wv1, const float* __restrict__ bv1,
                                               const float* __restrict__ Wv2, const float* __restrict__ bv2,
                                               float* __restrict__ out) {
    int lane = threadIdx.x & 63;
    int m = blockIdx.x * 4 + (threadIdx.x >> 6);   // 0..1023
    const float4* hv = (const float4*)(hs + m * 256);
    const float4* wp = (const float4*)(Wp1 + lane * 256);
    const float4* wq = (const float4*)(Wv1 + lane * 256);
    float ap = 0.f, av = 0.f;
#pragma unroll 8
    for (int k = 0; k < 64; ++k) {
        float4 h4 = hv[k];
        float4 p4 = wp[k];
        float4 q4 = wq[k];
        ap += h4.x * p4.x + h4.y * p4.y + h4.z * p4.z + h4.w * p4.w;
        av += h4.x * q4.x + h4.y * q4.y + h4.z * q4.z + h4.w * q4.w;
    }
    float hp = tanhf(ap + bp1[lane]);
    float hq = tanhf(av + bv1[lane]);
#pragma unroll
    for (int j = 0; j < 5; ++j) {
        float s = hp * Wp2[j * 64 + lane];
        s += __shfl_xor(s, 1); s += __shfl_xor(s, 2); s += __shfl_xor(s, 4);
        s += __shfl_xor(s, 8); s += __shfl_xor(s, 16); s += __shfl_xor(s, 32);
        if (lane == 0) out[m * 5 + j] = s + bp2[j];
    }
    float s = hq * Wv2[lane];
    s += __shfl_xor(s, 1); s += __shfl_xor(s, 2); s += __shfl_xor(s, 4);
    s += __shfl_xor(s, 8); s += __shfl_xor(s, 16); s += __shfl_xor(s, 32);
    if (lane == 0) out[5120 + m] = s + bv2[0];

    int g = blockIdx.x * 256 + threadIdx.x;
    if (g < 8192) {
        out[6144 + g] = hs[31 * 8192 + g];          // hT
        out[6144 + 8192 + g] = cb[g];               // cT
    }
}

extern "C" void kernel_launch(void* const* d_in, const int* in_sizes, int n_in,
                              void* d_out, int out_size, void* d_ws, size_t ws_size,
                              hipStream_t stream) {
    const float* image = (const float*)d_in[0];
    const int*   act   = (const int*)d_in[1];
    const float* done  = (const float*)d_in[2];
    const float* h0    = (const float*)d_in[3];
    const float* c0    = (const float*)d_in[4];
    const float* W1    = (const float*)d_in[5];
    const float* b1    = (const float*)d_in[6];
    const float* W2    = (const float*)d_in[7];
    const float* b2    = (const float*)d_in[8];
    const float* W3    = (const float*)d_in[9];
    const float* b3    = (const float*)d_in[10];
    const float* Wfc   = (const float*)d_in[11];
    const float* bfc   = (const float*)d_in[12];
    const float* Wih   = (const float*)d_in[13];
    const float* Whh   = (const float*)d_in[14];
    const float* bih   = (const float*)d_in[15];
    const float* bhh   = (const float*)d_in[16];
    const float* Wp1   = (const float*)d_in[17];
    const float* bp1   = (const float*)d_in[18];
    const float* Wp2   = (const float*)d_in[19];
    const float* bp2   = (const float*)d_in[20];
    const float* Wv1   = (const float*)d_in[21];
    const float* bv1   = (const float*)d_in[22];
    const float* Wv2   = (const float*)d_in[23];
    const float* bv2   = (const float*)d_in[24];
    float* out = (float*)d_out;
    char* base = (char*)d_ws;

    // ---- workspace layout (bytes) ----
    unsigned short* a1   = (unsigned short*)(base);             // 26,214,400
    unsigned short* a2   = (unsigned short*)(base + 26214432);  // 10,616,832
    unsigned short* W2p  = (unsigned short*)(base + 36831328);
    unsigned short* W3p  = W2p + 32768;
    unsigned short* Wfcp = W2p + 98304;
    unsigned short* Wihp = W2p + 1703936;
    unsigned short* W1p  = (unsigned short*)(base + 41287776);  // 12,288
    unsigned short* Whhp = (unsigned short*)(base + 41300064);  // 524,288
    unsigned short* hma0 = (unsigned short*)(base + 41824352);  // 16,384
    unsigned short* hma1 = (unsigned short*)(base + 41840736);  // 16,384
    unsigned short* a3   = (unsigned short*)(base);             // overlays dead a1
    unsigned short* feat = (unsigned short*)(base + 6422528);
    float* gx = (float*)(base + 7471104);
    float* hs = (float*)(base + 11665408);
    float* cb = (float*)(base + 12713984);

    k_prep<<<9752, 256, 0, stream>>>(W2, W3, Wfc, Wih, W1, Whh, W2p, W3p, Wfcp, Wihp, W1p, Whhp);
    k_conv1<<<3200, 256, 0, stream>>>(image, W1p, b1, a1);
    k_conv2<<<648, 256, 0, stream>>>(a1, W2p, b2, a2);
    k_conv3<<<392, 256, 0, stream>>>(a2, W3p, b3, a3);
    k_fc<<<dim3(32, 8), 256, 0, stream>>>(a3, Wfcp, bfc, feat);
    k_gx<<<dim3(32, 16), 256, 0, stream>>>(feat, Wihp, Wih, bih, bhh, act, gx);
    k_lstm_init<<<16, 256, 0, stream>>>(h0, c0, done, hma0, cb);
    for (int t = 0; t < 32; ++t) {
        const unsigned short* hin = (t & 1) ? hma1 : hma0;
        unsigned short* hout = (t & 1) ? hma0 : hma1;
        k_lstm_step<<<16, 256, 0, stream>>>(t, hin, hout, done, gx, Whhp, cb, hs);
    }
    k_heads<<<256, 256, 0, stream>>>(hs, cb, Wp1, bp1, Wp2, bp2, Wv1, bv1, Wv2, bv2, out);
}

// Round 8
// 479.836 us; speedup vs baseline: 1.4271x; 1.1047x over previous
//
#include <hip/hip_runtime.h>
#include <math.h>

typedef float  f4v __attribute__((ext_vector_type(4)));
typedef short  s8v __attribute__((ext_vector_type(8)));
typedef int    i4v __attribute__((ext_vector_type(4)));

__device__ __forceinline__ float sigm(float x) { return 1.f / (1.f + expf(-x)); }
__device__ __forceinline__ unsigned short f2bf(float f) {
    unsigned int u = __float_as_uint(f);
    return (unsigned short)((u + 0x7FFF + ((u >> 16) & 1)) >> 16);   // RTNE
}
__device__ __forceinline__ s8v pack8(float4 a, float4 b) {
    union { unsigned short u[8]; s8v v; } r;
    r.u[0] = f2bf(a.x); r.u[1] = f2bf(a.y); r.u[2] = f2bf(a.z); r.u[3] = f2bf(a.w);
    r.u[4] = f2bf(b.x); r.u[5] = f2bf(b.y); r.u[6] = f2bf(b.z); r.u[7] = f2bf(b.w);
    return r.v;
}

// ---------------- amax over Whh (for i8 quantization scale) ----------------
__global__ __launch_bounds__(256) void k_amax(const float* __restrict__ Whh,
                                              unsigned int* __restrict__ amax_bits) {
    int i = blockIdx.x * 256 + threadIdx.x;          // grid 1024 -> 262144
    float v = fabsf(Whh[i]);
#pragma unroll
    for (int o = 1; o < 64; o <<= 1) v = fmaxf(v, __shfl_xor(v, o));
    if ((threadIdx.x & 63) == 0) atomicMax(amax_bits, __float_as_uint(v));
}

// ---------------- prep: pack weights (bf16 GEMM layouts; Whh -> i8) ----------------
__global__ __launch_bounds__(256) void k_prep(const float* __restrict__ W2, const float* __restrict__ W3,
                                              const float* __restrict__ Wfc, const float* __restrict__ Wih,
                                              const float* __restrict__ W1, const float* __restrict__ Whh,
                                              const unsigned int* __restrict__ amax_bits,
                                              unsigned short* __restrict__ W2p, unsigned short* __restrict__ W3p,
                                              unsigned short* __restrict__ Wfcp, unsigned short* __restrict__ Wihp,
                                              unsigned short* __restrict__ W1p, signed char* __restrict__ Wq) {
    int i = blockIdx.x * 256 + threadIdx.x;
    if (i < 32768) {
        W2p[i] = f2bf(W2[i]);
    } else if (i < 98304) {
        int j = i - 32768;
        int co = j >> 10, r = j & 1023, ci = r >> 4, s = r & 15, ky = s >> 2, kx = s & 3;
        W3p[j] = (ky < 3 && kx < 3) ? f2bf(W3[((co * 64 + ci) * 3 + ky) * 3 + kx]) : (unsigned short)0;
    } else if (i < 1703936) {
        int j = i - 98304;
        Wfcp[j] = f2bf(Wfc[j]);
    } else if (i < 2228224) {
        int j = i - 1703936;
        int n = j >> 9, k = j & 511;
        Wihp[j] = f2bf(Wih[n * 517 + k]);
    } else if (i < 2234368) {
        int j = i - 2228224;
        W1p[j] = f2bf(W1[j] * (1.f / 255.f));
    } else if (i < 2496512) {
        int j = i - 2234368;
        float amax = __uint_as_float(amax_bits[0]);
        float s = 127.f / amax;
        int qv = (int)rintf(Whh[j] * s);
        qv = qv > 127 ? 127 : (qv < -127 ? -127 : qv);
        Wq[j] = (signed char)qv;                     // [1024][256] natural
    }
}

// ---------------- conv1 (MFMA): M=409600, N=32, K=192; 4 pixels/lane for MLP ----------------
__global__ __launch_bounds__(256) void k_conv1(const float* __restrict__ img,
                                               const unsigned short* __restrict__ Bw,
                                               const float* __restrict__ bias,
                                               unsigned short* __restrict__ out) {
    __shared__ unsigned short c1s[32][260];
    int lane = threadIdx.x & 63, w = threadIdx.x >> 6;
    int l15 = lane & 15, q = lane >> 4;
    int m0 = blockIdx.x * 256;
    const float* Ap[4];
#pragma unroll
    for (int mf = 0; mf < 4; ++mf) {
        int m = m0 + w * 64 + mf * 16 + l15;
        int im = m / 400, p = m - im * 400;
        int oy = p / 20, ox = p - oy * 20;
        Ap[mf] = img + im * 21168 + oy * 336 + ox * 4;
    }
    const unsigned short* Bp0 = Bw + l15 * 192 + q * 8;
    const unsigned short* Bp1 = Bw + (16 + l15) * 192 + q * 8;
    s8v bf0[6], bf1[6];
#pragma unroll
    for (int ks = 0; ks < 6; ++ks) {
        bf0[ks] = *(const s8v*)(Bp0 + ks * 32);
        bf1[ks] = *(const s8v*)(Bp1 + ks * 32);
    }
    f4v acc[8];
#pragma unroll
    for (int i = 0; i < 8; ++i) acc[i] = (f4v){0.f, 0.f, 0.f, 0.f};
#pragma unroll
    for (int ks = 0; ks < 6; ++ks) {
        int k0 = ks * 32 + q * 8;
        int c = k0 >> 6, ky = (k0 >> 3) & 7;
        int roff = c * 7056 + ky * 84;
        s8v ua[4];
#pragma unroll
        for (int mf = 0; mf < 4; ++mf) {
            float4 a0 = *(const float4*)(Ap[mf] + roff);
            float4 a1 = *(const float4*)(Ap[mf] + roff + 4);
            ua[mf] = pack8(a0, a1);
        }
#pragma unroll
        for (int mf = 0; mf < 4; ++mf) {
            acc[mf * 2 + 0] = __builtin_amdgcn_mfma_f32_16x16x32_bf16(ua[mf], bf0[ks], acc[mf * 2 + 0], 0, 0, 0);
            acc[mf * 2 + 1] = __builtin_amdgcn_mfma_f32_16x16x32_bf16(ua[mf], bf1[ks], acc[mf * 2 + 1], 0, 0, 0);
        }
    }
#pragma unroll
    for (int nf = 0; nf < 2; ++nf) {
        int n = nf * 16 + l15;
        float b = bias[n];
#pragma unroll
        for (int mf = 0; mf < 4; ++mf) {
#pragma unroll
            for (int r = 0; r < 4; ++r) {
                int ml = w * 64 + mf * 16 + q * 4 + r;
                float v = acc[mf * 2 + nf][r] + b;
                c1s[n][ml] = f2bf(v > 0.f ? v : 0.f);
            }
        }
    }
    __syncthreads();
#pragma unroll
    for (int seg = 0; seg < 32; ++seg) {
        int flat = seg * 256 + threadIdx.x;
        int n = flat >> 8, ml = flat & 255;
        int m = m0 + ml;
        int im = m / 400, p = m - im * 400;
        out[(im * 32 + n) * 400 + p] = c1s[n][ml];
    }
}

// ---------------- conv2 (MFMA): M=82944, N=64, K=512; LDS-staged epilogue ----------------
__global__ __launch_bounds__(256) void k_conv2(const unsigned short* __restrict__ A,
                                               const unsigned short* __restrict__ Bw,
                                               const float* __restrict__ bias,
                                               unsigned short* __restrict__ out) {
    __shared__ unsigned short c2s[64][136];
    int lane = threadIdx.x & 63, w = threadIdx.x >> 6;
    int l15 = lane & 15, q = lane >> 4;
    int m0 = blockIdx.x * 128;
    int ma = m0 + w * 32 + l15, mb = ma + 16;
    int ia = ma / 81, pa = ma - ia * 81; int oya = pa / 9, oxa = pa - oya * 9;
    int ib = mb / 81, pb = mb - ib * 81; int oyb = pb / 9, oxb = pb - oyb * 9;
    const unsigned short* Aa = A + ia * 12800 + oya * 40 + oxa * 2 + (q & 1) * 40;
    const unsigned short* Ab = A + ib * 12800 + oyb * 40 + oxb * 2 + (q & 1) * 40;
    int ci0 = q >> 1;
    const unsigned short* B0 = Bw + (l15) * 512 + q * 8;
    const unsigned short* B1 = Bw + (16 + l15) * 512 + q * 8;
    const unsigned short* B2 = Bw + (32 + l15) * 512 + q * 8;
    const unsigned short* B3 = Bw + (48 + l15) * 512 + q * 8;
    f4v acc[8];
#pragma unroll
    for (int i = 0; i < 8; ++i) acc[i] = (f4v){0.f, 0.f, 0.f, 0.f};
    for (int c = 0; c < 16; ++c) {
        int ci = 2 * c + ci0;
        const unsigned short* pa_ = Aa + ci * 400;
        const unsigned short* pb_ = Ab + ci * 400;
        union { unsigned int u[4]; s8v v; } ua, ub;
        ua.u[0] = *(const unsigned int*)(pa_);      ua.u[1] = *(const unsigned int*)(pa_ + 2);
        ua.u[2] = *(const unsigned int*)(pa_ + 20); ua.u[3] = *(const unsigned int*)(pa_ + 22);
        ub.u[0] = *(const unsigned int*)(pb_);      ub.u[1] = *(const unsigned int*)(pb_ + 2);
        ub.u[2] = *(const unsigned int*)(pb_ + 20); ub.u[3] = *(const unsigned int*)(pb_ + 22);
        s8v b0 = *(const s8v*)B0, b1 = *(const s8v*)B1, b2 = *(const s8v*)B2, b3 = *(const s8v*)B3;
        B0 += 32; B1 += 32; B2 += 32; B3 += 32;
        acc[0] = __builtin_amdgcn_mfma_f32_16x16x32_bf16(ua.v, b0, acc[0], 0, 0, 0);
        acc[1] = __builtin_amdgcn_mfma_f32_16x16x32_bf16(ua.v, b1, acc[1], 0, 0, 0);
        acc[2] = __builtin_amdgcn_mfma_f32_16x16x32_bf16(ua.v, b2, acc[2], 0, 0, 0);
        acc[3] = __builtin_amdgcn_mfma_f32_16x16x32_bf16(ua.v, b3, acc[3], 0, 0, 0);
        acc[4] = __builtin_amdgcn_mfma_f32_16x16x32_bf16(ub.v, b0, acc[4], 0, 0, 0);
        acc[5] = __builtin_amdgcn_mfma_f32_16x16x32_bf16(ub.v, b1, acc[5], 0, 0, 0);
        acc[6] = __builtin_amdgcn_mfma_f32_16x16x32_bf16(ub.v, b2, acc[6], 0, 0, 0);
        acc[7] = __builtin_amdgcn_mfma_f32_16x16x32_bf16(ub.v, b3, acc[7], 0, 0, 0);
    }
#pragma unroll
    for (int nf = 0; nf < 4; ++nf) {
        int n = nf * 16 + l15;
        float b = bias[n];
#pragma unroll
        for (int mf = 0; mf < 2; ++mf) {
#pragma unroll
            for (int r = 0; r < 4; ++r) {
                int ml = w * 32 + mf * 16 + q * 4 + r;
                float v = acc[mf * 4 + nf][r] + b;
                c2s[n][ml] = f2bf(v > 0.f ? v : 0.f);
            }
        }
    }
    __syncthreads();
#pragma unroll
    for (int seg = 0; seg < 32; ++seg) {
        int flat = seg * 256 + threadIdx.x;
        int n = flat >> 7, ml = flat & 127;
        int m = m0 + ml;
        int im = m / 81, p = m - im * 81;
        out[im * 5184 + n * 81 + p] = c2s[n][ml];
    }
}

// ---------------- conv3 (MFMA): M=50176, N=64, K=64ci*16slots; LDS-staged epilogue ----------------
__global__ __launch_bounds__(256) void k_conv3(const unsigned short* __restrict__ A,
                                               const unsigned short* __restrict__ Bw,
                                               const float* __restrict__ bias,
                                               unsigned short* __restrict__ out) {
    __shared__ unsigned short c3s[64][136];
    int lane = threadIdx.x & 63, w = threadIdx.x >> 6;
    int l15 = lane & 15, q = lane >> 4;
    int m0 = blockIdx.x * 128;
    int ma = m0 + w * 32 + l15, mb = ma + 16;
    int ia = ma / 49, pa = ma - ia * 49; int oya = pa / 7, oxa = pa - oya * 7;
    int ib = mb / 49, pb = mb - ib * 49; int oyb = pb / 7, oxb = pb - oyb * 7;
    int ky0 = (q & 1) * 2;
    int r0off = ky0 * 9;
    int r1off = (ky0 + 1 > 2 ? 2 : ky0 + 1) * 9;
    int zr = q & 1;
    const unsigned short* Aa = A + ia * 5184 + oya * 9 + oxa;
    const unsigned short* Ab = A + ib * 5184 + oyb * 9 + oxb;
    int ci0 = q >> 1;
    const unsigned short* B0 = Bw + (l15) * 1024 + q * 8;
    const unsigned short* B1 = Bw + (16 + l15) * 1024 + q * 8;
    const unsigned short* B2 = Bw + (32 + l15) * 1024 + q * 8;
    const unsigned short* B3 = Bw + (48 + l15) * 1024 + q * 8;
    f4v acc[8];
#pragma unroll
    for (int i = 0; i < 8; ++i) acc[i] = (f4v){0.f, 0.f, 0.f, 0.f};
    for (int c = 0; c < 32; ++c) {
        int ci = 2 * c + ci0;
        const unsigned short* pa_ = Aa + ci * 81;
        const unsigned short* pb_ = Ab + ci * 81;
        s8v av, bv;
        av[0] = pa_[r0off]; av[1] = pa_[r0off + 1]; av[2] = pa_[r0off + 2]; av[3] = 0;
        av[4] = zr ? (short)0 : (short)pa_[r1off];
        av[5] = zr ? (short)0 : (short)pa_[r1off + 1];
        av[6] = zr ? (short)0 : (short)pa_[r1off + 2];
        av[7] = 0;
        bv[0] = pb_[r0off]; bv[1] = pb_[r0off + 1]; bv[2] = pb_[r0off + 2]; bv[3] = 0;
        bv[4] = zr ? (short)0 : (short)pb_[r1off];
        bv[5] = zr ? (short)0 : (short)pb_[r1off + 1];
        bv[6] = zr ? (short)0 : (short)pb_[r1off + 2];
        bv[7] = 0;
        s8v b0 = *(const s8v*)B0, b1 = *(const s8v*)B1, b2 = *(const s8v*)B2, b3 = *(const s8v*)B3;
        B0 += 32; B1 += 32; B2 += 32; B3 += 32;
        acc[0] = __builtin_amdgcn_mfma_f32_16x16x32_bf16(av, b0, acc[0], 0, 0, 0);
        acc[1] = __builtin_amdgcn_mfma_f32_16x16x32_bf16(av, b1, acc[1], 0, 0, 0);
        acc[2] = __builtin_amdgcn_mfma_f32_16x16x32_bf16(av, b2, acc[2], 0, 0, 0);
        acc[3] = __builtin_amdgcn_mfma_f32_16x16x32_bf16(av, b3, acc[3], 0, 0, 0);
        acc[4] = __builtin_amdgcn_mfma_f32_16x16x32_bf16(bv, b0, acc[4], 0, 0, 0);
        acc[5] = __builtin_amdgcn_mfma_f32_16x16x32_bf16(bv, b1, acc[5], 0, 0, 0);
        acc[6] = __builtin_amdgcn_mfma_f32_16x16x32_bf16(bv, b2, acc[6], 0, 0, 0);
        acc[7] = __builtin_amdgcn_mfma_f32_16x16x32_bf16(bv, b3, acc[7], 0, 0, 0);
    }
#pragma unroll
    for (int nf = 0; nf < 4; ++nf) {
        int n = nf * 16 + l15;
        float b = bias[n];
#pragma unroll
        for (int mf = 0; mf < 2; ++mf) {
#pragma unroll
            for (int r = 0; r < 4; ++r) {
                int ml = w * 32 + mf * 16 + q * 4 + r;
                float v = acc[mf * 4 + nf][r] + b;
                c3s[n][ml] = f2bf(v > 0.f ? v : 0.f);
            }
        }
    }
    __syncthreads();
#pragma unroll
    for (int seg = 0; seg < 32; ++seg) {
        int flat = seg * 256 + threadIdx.x;
        int n = flat >> 7, ml = flat & 127;
        int m = m0 + ml;
        int im = m / 49, p = m - im * 49;
        out[im * 3136 + n * 49 + p] = c3s[n][ml];
    }
}

// ---------------- FC (MFMA) ----------------
__global__ __launch_bounds__(256) void k_fc(const unsigned short* __restrict__ A,
                                            const unsigned short* __restrict__ Bw,
                                            const float* __restrict__ bias,
                                            unsigned short* __restrict__ out) {
    int lane = threadIdx.x & 63, w = threadIdx.x >> 6;
    int l15 = lane & 15, q = lane >> 4;
    int m0 = blockIdx.x * 32 + (w & 1) * 16;
    int n0 = blockIdx.y * 64 + (w >> 1) * 32;
    const unsigned short* Ap = A + (m0 + l15) * 3136 + q * 8;
    const unsigned short* B0 = Bw + (n0 + l15) * 3136 + q * 8;
    const unsigned short* B1 = B0 + 16 * 3136;
    f4v acc0 = (f4v){0.f, 0.f, 0.f, 0.f}, acc1 = (f4v){0.f, 0.f, 0.f, 0.f};
    for (int c = 0; c < 98; ++c) {
        s8v av = *(const s8v*)Ap;
        s8v b0 = *(const s8v*)B0;
        s8v b1 = *(const s8v*)B1;
        Ap += 32; B0 += 32; B1 += 32;
        acc0 = __builtin_amdgcn_mfma_f32_16x16x32_bf16(av, b0, acc0, 0, 0, 0);
        acc1 = __builtin_amdgcn_mfma_f32_16x16x32_bf16(av, b1, acc1, 0, 0, 0);
    }
    float bi0 = bias[n0 + l15], bi1 = bias[n0 + 16 + l15];
#pragma unroll
    for (int r = 0; r < 4; ++r) {
        int m = m0 + q * 4 + r;
        float v0 = acc0[r] + bi0; v0 = v0 > 0.f ? v0 : 0.f;
        float v1 = acc1[r] + bi1; v1 = v1 > 0.f ? v1 : 0.f;
        out[m * 512 + n0 + l15] = f2bf(v0);
        out[m * 512 + n0 + 16 + l15] = f2bf(v1);
    }
}

// ---------------- gx (MFMA) ----------------
__global__ __launch_bounds__(256) void k_gx(const unsigned short* __restrict__ A,
                                            const unsigned short* __restrict__ Bw,
                                            const float* __restrict__ Wih,
                                            const float* __restrict__ bih,
                                            const float* __restrict__ bhh,
                                            const int* __restrict__ act,
                                            float* __restrict__ out) {
    int lane = threadIdx.x & 63, w = threadIdx.x >> 6;
    int l15 = lane & 15, q = lane >> 4;
    int m0 = blockIdx.x * 32 + (w & 1) * 16;
    int n0 = blockIdx.y * 64 + (w >> 1) * 32;
    const unsigned short* Ap = A + (m0 + l15) * 512 + q * 8;
    const unsigned short* B0 = Bw + (n0 + l15) * 512 + q * 8;
    const unsigned short* B1 = B0 + 16 * 512;
    f4v acc0 = (f4v){0.f, 0.f, 0.f, 0.f}, acc1 = (f4v){0.f, 0.f, 0.f, 0.f};
    for (int c = 0; c < 16; ++c) {
        s8v av = *(const s8v*)Ap;
        s8v b0 = *(const s8v*)B0;
        s8v b1 = *(const s8v*)B1;
        Ap += 32; B0 += 32; B1 += 32;
        acc0 = __builtin_amdgcn_mfma_f32_16x16x32_bf16(av, b0, acc0, 0, 0, 0);
        acc1 = __builtin_amdgcn_mfma_f32_16x16x32_bf16(av, b1, acc1, 0, 0, 0);
    }
    int na = n0 + l15, nb = n0 + 16 + l15;
    float ca = bih[na] + bhh[na], cb_ = bih[nb] + bhh[nb];
#pragma unroll
    for (int r = 0; r < 4; ++r) {
        int m = m0 + q * 4 + r;
        int a = act[m];
        out[m * 1024 + na] = acc0[r] + Wih[na * 517 + 512 + a] + ca;
        out[m * 1024 + nb] = acc1[r] + Wih[nb * 517 + 512 + a] + cb_;
    }
}

// ---------------- fused LSTM, batch-split: 8 wgs x 4 envs, NO inter-wg communication ----------------
// Each wg owns batch rows b0..b0+3 (independent recurrences). Whh i8 register-resident:
// wave w holds B-frags for n-rows w*64..w*64+63 (4 sets x 4 kfrags, 64 VGPR).
// Per step: h(i8, LDS A-frag layout, rows 0-3 live) x Whh -> gates via LDS -> pointwise -> requantize h.
__global__ __launch_bounds__(1024) void k_lstm_all(const float* __restrict__ h0,
                                                   const float* __restrict__ c0,
                                                   const float* __restrict__ done,
                                                   const float* __restrict__ gx,
                                                   const signed char* __restrict__ Wq,
                                                   const unsigned int* __restrict__ amax_bits,
                                                   float* __restrict__ hs,
                                                   float* __restrict__ cb) {
    int b0 = blockIdx.x * 4;
    int tid = threadIdx.x;
    int w = tid >> 6, lane = tid & 63;
    int l15 = lane & 15, q = lane >> 4;
    __shared__ float gbuf[1024][5];                  // [n_out][b], pad 5 for conflict-free strided read
    __shared__ float cst[4][256];
    __shared__ signed char hA[4][64][16];            // [kfrag][lane][16 i8] A-operand layout

    // load weights into registers: row = w*64 + s*16 + l15; k = kf*64 + q*16 .. +16
    i4v wfr[4][4];
    const signed char* wb = Wq + (w * 64 + l15) * 256 + q * 16;
#pragma unroll
    for (int s = 0; s < 4; ++s)
#pragma unroll
        for (int kf = 0; kf < 4; ++kf)
            wfr[s][kf] = *(const i4v*)(wb + s * 16 * 256 + kf * 64);
    float sw = __uint_as_float(amax_bits[0]) * (1.f / (127.f * 127.f));

    // zero hA (lanes l15>=4 never written later), then init cst + hA for t=0
    ((int*)hA)[tid] = 0;
    __syncthreads();
    {
        int b = tid >> 8, u = tid & 255;
        cst[b][u] = c0[(b0 + b) * 256 + u];
        float m0v = 1.f - done[b0 + b];
        float hv = h0[(b0 + b) * 256 + u] * m0v;
        hv = hv > 1.f ? 1.f : (hv < -1.f ? -1.f : hv);
        int qh = (int)rintf(hv * 127.f);
        hA[u >> 6][((u >> 4) & 3) * 16 + b][u & 15] = (signed char)qh;
    }
    __syncthreads();

    for (int t = 0; t < 32; ++t) {
        i4v acc[4];
#pragma unroll
        for (int s = 0; s < 4; ++s) acc[s] = (i4v){0, 0, 0, 0};
#pragma unroll
        for (int kf = 0; kf < 4; ++kf) {
            i4v a = *(const i4v*)&hA[kf][lane][0];
#pragma unroll
            for (int s = 0; s < 4; ++s)
                acc[s] = __builtin_amdgcn_mfma_i32_16x16x64_i8(a, wfr[s][kf], acc[s], 0, 0, 0);
        }
        if (q == 0) {                                // C rows 0-3 (= batch rows) live in q==0 lanes
#pragma unroll
            for (int s = 0; s < 4; ++s) {
                int n = w * 64 + s * 16 + l15;
#pragma unroll
                for (int r = 0; r < 4; ++r)
                    gbuf[n][r] = (float)acc[s][r];
            }
        }
        __syncthreads();
        {
            int u = tid & 255, b = tid >> 8;
            const float* gr = gx + (t * 32 + b0 + b) * 1024;
            float gi = gbuf[u][b] * sw + gr[u];
            float gf = gbuf[256 + u][b] * sw + gr[256 + u];
            float gg = gbuf[512 + u][b] * sw + gr[512 + u];
            float go = gbuf[768 + u][b] * sw + gr[768 + u];
            float m = 1.f - done[t * 32 + b0 + b];
            float cm = cst[b][u] * m;
            float cn = sigm(gf) * cm + sigm(gi) * tanhf(gg);
            float hn = sigm(go) * tanhf(cn);
            cst[b][u] = cn;
            hs[t * 8192 + (b0 + b) * 256 + u] = hn;
            int qh = 0;
            if (t < 31) {
                float m2 = 1.f - done[(t + 1) * 32 + b0 + b];
                float hv = hn * m2;                  // |h|<1 by construction
                qh = (int)rintf(hv * 127.f);
            }
            hA[u >> 6][((u >> 4) & 3) * 16 + b][u & 15] = (signed char)qh;
        }
        __syncthreads();
    }
    int u = tid & 255, b = tid >> 8;
    cb[(b0 + b) * 256 + u] = cst[b][u];
}

// ---------------- heads (fp32, unchanged) ----------------
__global__ __launch_bounds__(256) void k_heads(const float* __restrict__ hs,
                                               const float* __restrict__ cb,
                                               const float* __restrict__ Wp1, const float* __restrict__ bp1,
                                               const float* __restrict__ Wp2, const float* __restrict__ bp2,
                                               const float* __restrict__ Wv1, const float* __restrict__ bv1,
                                               const float* __restrict__ Wv2, const float* __restrict__ bv2,
                                               float* __restrict__ out) {
    int lane = threadIdx.x & 63;
    int m = blockIdx.x * 4 + (threadIdx.x >> 6);   // 0..1023
    const float4* hv = (const float4*)(hs + m * 256);
    const float4* wp = (const float4*)(Wp1 + lane * 256);
    const float4* wq = (const float4*)(Wv1 + lane * 256);
    float ap = 0.f, av = 0.f;
#pragma unroll 8
    for (int k = 0; k < 64; ++k) {
        float4 h4 = hv[k];
        float4 p4 = wp[k];
        float4 q4 = wq[k];
        ap += h4.x * p4.x + h4.y * p4.y + h4.z * p4.z + h4.w * p4.w;
        av += h4.x * q4.x + h4.y * q4.y + h4.z * q4.z + h4.w * q4.w;
    }
    float hp = tanhf(ap + bp1[lane]);
    float hq = tanhf(av + bv1[lane]);
#pragma unroll
    for (int j = 0; j < 5; ++j) {
        float s = hp * Wp2[j * 64 + lane];
        s += __shfl_xor(s, 1); s += __shfl_xor(s, 2); s += __shfl_xor(s, 4);
        s += __shfl_xor(s, 8); s += __shfl_xor(s, 16); s += __shfl_xor(s, 32);
        if (lane == 0) out[m * 5 + j] = s + bp2[j];
    }
    float s = hq * Wv2[lane];
    s += __shfl_xor(s, 1); s += __shfl_xor(s, 2); s += __shfl_xor(s, 4);
    s += __shfl_xor(s, 8); s += __shfl_xor(s, 16); s += __shfl_xor(s, 32);
    if (lane == 0) out[5120 + m] = s + bv2[0];

    int g = blockIdx.x * 256 + threadIdx.x;
    if (g < 8192) {
        out[6144 + g] = hs[31 * 8192 + g];          // hT
        out[6144 + 8192 + g] = cb[g];               // cT
    }
}

extern "C" void kernel_launch(void* const* d_in, const int* in_sizes, int n_in,
                              void* d_out, int out_size, void* d_ws, size_t ws_size,
                              hipStream_t stream) {
    const float* image = (const float*)d_in[0];
    const int*   act   = (const int*)d_in[1];
    const float* done  = (const float*)d_in[2];
    const float* h0    = (const float*)d_in[3];
    const float* c0    = (const float*)d_in[4];
    const float* W1    = (const float*)d_in[5];
    const float* b1    = (const float*)d_in[6];
    const float* W2    = (const float*)d_in[7];
    const float* b2    = (const float*)d_in[8];
    const float* W3    = (const float*)d_in[9];
    const float* b3    = (const float*)d_in[10];
    const float* Wfc   = (const float*)d_in[11];
    const float* bfc   = (const float*)d_in[12];
    const float* Wih   = (const float*)d_in[13];
    const float* Whh   = (const float*)d_in[14];
    const float* bih   = (const float*)d_in[15];
    const float* bhh   = (const float*)d_in[16];
    const float* Wp1   = (const float*)d_in[17];
    const float* bp1   = (const float*)d_in[18];
    const float* Wp2   = (const float*)d_in[19];
    const float* bp2   = (const float*)d_in[20];
    const float* Wv1   = (const float*)d_in[21];
    const float* bv1   = (const float*)d_in[22];
    const float* Wv2   = (const float*)d_in[23];
    const float* bv2   = (const float*)d_in[24];
    float* out = (float*)d_out;
    char* base = (char*)d_ws;

    // ---- workspace layout (bytes) ----
    unsigned short* a1   = (unsigned short*)(base);             // 26,214,400
    unsigned short* a2   = (unsigned short*)(base + 26214432);  // 10,616,832
    unsigned short* W2p  = (unsigned short*)(base + 36831328);
    unsigned short* W3p  = W2p + 32768;
    unsigned short* Wfcp = W2p + 98304;
    unsigned short* Wihp = W2p + 1703936;
    unsigned short* W1p  = (unsigned short*)(base + 41287776);  // 12,288
    unsigned int*   amax = (unsigned int*)(base + 41300064);    // 4 (+pad)
    signed char*    Wq   = (signed char*)(base + 41300096);     // 262,144
    unsigned short* a3   = (unsigned short*)(base);             // overlays dead a1
    unsigned short* feat = (unsigned short*)(base + 6422528);
    float* gx = (float*)(base + 7471104);
    float* hs = (float*)(base + 11665408);
    float* cb = (float*)(base + 12713984);

    hipMemsetAsync(amax, 0, 4, stream);
    k_amax<<<1024, 256, 0, stream>>>(Whh, amax);
    k_prep<<<9752, 256, 0, stream>>>(W2, W3, Wfc, Wih, W1, Whh, amax, W2p, W3p, Wfcp, Wihp, W1p, Wq);
    k_conv1<<<1600, 256, 0, stream>>>(image, W1p, b1, a1);
    k_conv2<<<648, 256, 0, stream>>>(a1, W2p, b2, a2);
    k_conv3<<<392, 256, 0, stream>>>(a2, W3p, b3, a3);
    k_fc<<<dim3(32, 8), 256, 0, stream>>>(a3, Wfcp, bfc, feat);
    k_gx<<<dim3(32, 16), 256, 0, stream>>>(feat, Wihp, Wih, bih, bhh, act, gx);
    k_lstm_all<<<8, 1024, 0, stream>>>(h0, c0, done, gx, Wq, amax, hs, cb);
    k_heads<<<256, 256, 0, stream>>>(hs, cb, Wp1, bp1, Wp2, bp2, Wv1, bv1, Wv2, bv2, out);
}

// Round 9
// 454.215 us; speedup vs baseline: 1.5076x; 1.0564x over previous
//
#include <hip/hip_runtime.h>
#include <math.h>

typedef float  f4v __attribute__((ext_vector_type(4)));
typedef short  s8v __attribute__((ext_vector_type(8)));
typedef int    i4v __attribute__((ext_vector_type(4)));

__device__ __forceinline__ float sigm(float x) { return 1.f / (1.f + expf(-x)); }
__device__ __forceinline__ unsigned short f2bf(float f) {
    unsigned int u = __float_as_uint(f);
    return (unsigned short)((u + 0x7FFF + ((u >> 16) & 1)) >> 16);   // RTNE
}
__device__ __forceinline__ s8v pack8(float4 a, float4 b) {
    union { unsigned short u[8]; s8v v; } r;
    r.u[0] = f2bf(a.x); r.u[1] = f2bf(a.y); r.u[2] = f2bf(a.z); r.u[3] = f2bf(a.w);
    r.u[4] = f2bf(b.x); r.u[5] = f2bf(b.y); r.u[6] = f2bf(b.z); r.u[7] = f2bf(b.w);
    return r.v;
}

// ---------------- amax over Whh (for i8 quantization scale) ----------------
__global__ __launch_bounds__(256) void k_amax(const float* __restrict__ Whh,
                                              unsigned int* __restrict__ amax_bits) {
    int i = blockIdx.x * 256 + threadIdx.x;          // grid 1024 -> 262144
    float v = fabsf(Whh[i]);
#pragma unroll
    for (int o = 1; o < 64; o <<= 1) v = fmaxf(v, __shfl_xor(v, o));
    if ((threadIdx.x & 63) == 0) atomicMax(amax_bits, __float_as_uint(v));
}

// ---------------- prep: pack weights (bf16 GEMM layouts; Whh -> i8) ----------------
__global__ __launch_bounds__(256) void k_prep(const float* __restrict__ W2, const float* __restrict__ W3,
                                              const float* __restrict__ Wfc, const float* __restrict__ Wih,
                                              const float* __restrict__ W1, const float* __restrict__ Whh,
                                              const unsigned int* __restrict__ amax_bits,
                                              unsigned short* __restrict__ W2p, unsigned short* __restrict__ W3p,
                                              unsigned short* __restrict__ Wfcp, unsigned short* __restrict__ Wihp,
                                              unsigned short* __restrict__ W1p, signed char* __restrict__ Wq) {
    int i = blockIdx.x * 256 + threadIdx.x;
    if (i < 32768) {
        W2p[i] = f2bf(W2[i]);
    } else if (i < 98304) {
        int j = i - 32768;
        int co = j >> 10, r = j & 1023, ci = r >> 4, s = r & 15, ky = s >> 2, kx = s & 3;
        W3p[j] = (ky < 3 && kx < 3) ? f2bf(W3[((co * 64 + ci) * 3 + ky) * 3 + kx]) : (unsigned short)0;
    } else if (i < 1703936) {
        int j = i - 98304;
        Wfcp[j] = f2bf(Wfc[j]);
    } else if (i < 2228224) {
        int j = i - 1703936;
        int n = j >> 9, k = j & 511;
        Wihp[j] = f2bf(Wih[n * 517 + k]);
    } else if (i < 2234368) {
        int j = i - 2228224;
        W1p[j] = f2bf(W1[j] * (1.f / 255.f));
    } else if (i < 2496512) {
        int j = i - 2234368;
        float amax = __uint_as_float(amax_bits[0]);
        float s = 127.f / amax;
        int qv = (int)rintf(Whh[j] * s);
        qv = qv > 127 ? 127 : (qv < -127 ? -127 : qv);
        Wq[j] = (signed char)qv;                     // [1024][256] natural
    }
}

// ---------------- conv1 (MFMA): M=409600, N=32, K=192; 4 pixels/lane ----------------
__global__ __launch_bounds__(256) void k_conv1(const float* __restrict__ img,
                                               const unsigned short* __restrict__ Bw,
                                               const float* __restrict__ bias,
                                               unsigned short* __restrict__ out) {
    __shared__ unsigned short c1s[32][260];
    int lane = threadIdx.x & 63, w = threadIdx.x >> 6;
    int l15 = lane & 15, q = lane >> 4;
    int m0 = blockIdx.x * 256;
    const float* Ap[4];
#pragma unroll
    for (int mf = 0; mf < 4; ++mf) {
        int m = m0 + w * 64 + mf * 16 + l15;
        int im = m / 400, p = m - im * 400;
        int oy = p / 20, ox = p - oy * 20;
        Ap[mf] = img + im * 21168 + oy * 336 + ox * 4;
    }
    const unsigned short* Bp0 = Bw + l15 * 192 + q * 8;
    const unsigned short* Bp1 = Bw + (16 + l15) * 192 + q * 8;
    s8v bf0[6], bf1[6];
#pragma unroll
    for (int ks = 0; ks < 6; ++ks) {
        bf0[ks] = *(const s8v*)(Bp0 + ks * 32);
        bf1[ks] = *(const s8v*)(Bp1 + ks * 32);
    }
    f4v acc[8];
#pragma unroll
    for (int i = 0; i < 8; ++i) acc[i] = (f4v){0.f, 0.f, 0.f, 0.f};
#pragma unroll
    for (int ks = 0; ks < 6; ++ks) {
        int k0 = ks * 32 + q * 8;
        int c = k0 >> 6, ky = (k0 >> 3) & 7;
        int roff = c * 7056 + ky * 84;
        s8v ua[4];
#pragma unroll
        for (int mf = 0; mf < 4; ++mf) {
            float4 a0 = *(const float4*)(Ap[mf] + roff);
            float4 a1 = *(const float4*)(Ap[mf] + roff + 4);
            ua[mf] = pack8(a0, a1);
        }
#pragma unroll
        for (int mf = 0; mf < 4; ++mf) {
            acc[mf * 2 + 0] = __builtin_amdgcn_mfma_f32_16x16x32_bf16(ua[mf], bf0[ks], acc[mf * 2 + 0], 0, 0, 0);
            acc[mf * 2 + 1] = __builtin_amdgcn_mfma_f32_16x16x32_bf16(ua[mf], bf1[ks], acc[mf * 2 + 1], 0, 0, 0);
        }
    }
#pragma unroll
    for (int nf = 0; nf < 2; ++nf) {
        int n = nf * 16 + l15;
        float b = bias[n];
#pragma unroll
        for (int mf = 0; mf < 4; ++mf) {
#pragma unroll
            for (int r = 0; r < 4; ++r) {
                int ml = w * 64 + mf * 16 + q * 4 + r;
                float v = acc[mf * 2 + nf][r] + b;
                c1s[n][ml] = f2bf(v > 0.f ? v : 0.f);
            }
        }
    }
    __syncthreads();
#pragma unroll
    for (int seg = 0; seg < 32; ++seg) {
        int flat = seg * 256 + threadIdx.x;
        int n = flat >> 8, ml = flat & 255;
        int m = m0 + ml;
        int im = m / 400, p = m - im * 400;
        out[(im * 32 + n) * 400 + p] = c1s[n][ml];
    }
}

// ---------------- conv2 (MFMA): M=82944, N=64, K=512; LDS-staged epilogue ----------------
__global__ __launch_bounds__(256) void k_conv2(const unsigned short* __restrict__ A,
                                               const unsigned short* __restrict__ Bw,
                                               const float* __restrict__ bias,
                                               unsigned short* __restrict__ out) {
    __shared__ unsigned short c2s[64][136];
    int lane = threadIdx.x & 63, w = threadIdx.x >> 6;
    int l15 = lane & 15, q = lane >> 4;
    int m0 = blockIdx.x * 128;
    int ma = m0 + w * 32 + l15, mb = ma + 16;
    int ia = ma / 81, pa = ma - ia * 81; int oya = pa / 9, oxa = pa - oya * 9;
    int ib = mb / 81, pb = mb - ib * 81; int oyb = pb / 9, oxb = pb - oyb * 9;
    const unsigned short* Aa = A + ia * 12800 + oya * 40 + oxa * 2 + (q & 1) * 40;
    const unsigned short* Ab = A + ib * 12800 + oyb * 40 + oxb * 2 + (q & 1) * 40;
    int ci0 = q >> 1;
    const unsigned short* B0 = Bw + (l15) * 512 + q * 8;
    const unsigned short* B1 = Bw + (16 + l15) * 512 + q * 8;
    const unsigned short* B2 = Bw + (32 + l15) * 512 + q * 8;
    const unsigned short* B3 = Bw + (48 + l15) * 512 + q * 8;
    f4v acc[8];
#pragma unroll
    for (int i = 0; i < 8; ++i) acc[i] = (f4v){0.f, 0.f, 0.f, 0.f};
    for (int c = 0; c < 16; ++c) {
        int ci = 2 * c + ci0;
        const unsigned short* pa_ = Aa + ci * 400;
        const unsigned short* pb_ = Ab + ci * 400;
        union { unsigned int u[4]; s8v v; } ua, ub;
        ua.u[0] = *(const unsigned int*)(pa_);      ua.u[1] = *(const unsigned int*)(pa_ + 2);
        ua.u[2] = *(const unsigned int*)(pa_ + 20); ua.u[3] = *(const unsigned int*)(pa_ + 22);
        ub.u[0] = *(const unsigned int*)(pb_);      ub.u[1] = *(const unsigned int*)(pb_ + 2);
        ub.u[2] = *(const unsigned int*)(pb_ + 20); ub.u[3] = *(const unsigned int*)(pb_ + 22);
        s8v b0 = *(const s8v*)B0, b1 = *(const s8v*)B1, b2 = *(const s8v*)B2, b3 = *(const s8v*)B3;
        B0 += 32; B1 += 32; B2 += 32; B3 += 32;
        acc[0] = __builtin_amdgcn_mfma_f32_16x16x32_bf16(ua.v, b0, acc[0], 0, 0, 0);
        acc[1] = __builtin_amdgcn_mfma_f32_16x16x32_bf16(ua.v, b1, acc[1], 0, 0, 0);
        acc[2] = __builtin_amdgcn_mfma_f32_16x16x32_bf16(ua.v, b2, acc[2], 0, 0, 0);
        acc[3] = __builtin_amdgcn_mfma_f32_16x16x32_bf16(ua.v, b3, acc[3], 0, 0, 0);
        acc[4] = __builtin_amdgcn_mfma_f32_16x16x32_bf16(ub.v, b0, acc[4], 0, 0, 0);
        acc[5] = __builtin_amdgcn_mfma_f32_16x16x32_bf16(ub.v, b1, acc[5], 0, 0, 0);
        acc[6] = __builtin_amdgcn_mfma_f32_16x16x32_bf16(ub.v, b2, acc[6], 0, 0, 0);
        acc[7] = __builtin_amdgcn_mfma_f32_16x16x32_bf16(ub.v, b3, acc[7], 0, 0, 0);
    }
#pragma unroll
    for (int nf = 0; nf < 4; ++nf) {
        int n = nf * 16 + l15;
        float b = bias[n];
#pragma unroll
        for (int mf = 0; mf < 2; ++mf) {
#pragma unroll
            for (int r = 0; r < 4; ++r) {
                int ml = w * 32 + mf * 16 + q * 4 + r;
                float v = acc[mf * 4 + nf][r] + b;
                c2s[n][ml] = f2bf(v > 0.f ? v : 0.f);
            }
        }
    }
    __syncthreads();
#pragma unroll
    for (int seg = 0; seg < 32; ++seg) {
        int flat = seg * 256 + threadIdx.x;
        int n = flat >> 7, ml = flat & 127;
        int m = m0 + ml;
        int im = m / 81, p = m - im * 81;
        out[im * 5184 + n * 81 + p] = c2s[n][ml];
    }
}

// ---------------- conv3 (MFMA): M=50176, N=64, K=64ci*16slots; LDS-staged epilogue ----------------
__global__ __launch_bounds__(256) void k_conv3(const unsigned short* __restrict__ A,
                                               const unsigned short* __restrict__ Bw,
                                               const float* __restrict__ bias,
                                               unsigned short* __restrict__ out) {
    __shared__ unsigned short c3s[64][136];
    int lane = threadIdx.x & 63, w = threadIdx.x >> 6;
    int l15 = lane & 15, q = lane >> 4;
    int m0 = blockIdx.x * 128;
    int ma = m0 + w * 32 + l15, mb = ma + 16;
    int ia = ma / 49, pa = ma - ia * 49; int oya = pa / 7, oxa = pa - oya * 7;
    int ib = mb / 49, pb = mb - ib * 49; int oyb = pb / 7, oxb = pb - oyb * 7;
    int ky0 = (q & 1) * 2;
    int r0off = ky0 * 9;
    int r1off = (ky0 + 1 > 2 ? 2 : ky0 + 1) * 9;
    int zr = q & 1;
    const unsigned short* Aa = A + ia * 5184 + oya * 9 + oxa;
    const unsigned short* Ab = A + ib * 5184 + oyb * 9 + oxb;
    int ci0 = q >> 1;
    const unsigned short* B0 = Bw + (l15) * 1024 + q * 8;
    const unsigned short* B1 = Bw + (16 + l15) * 1024 + q * 8;
    const unsigned short* B2 = Bw + (32 + l15) * 1024 + q * 8;
    const unsigned short* B3 = Bw + (48 + l15) * 1024 + q * 8;
    f4v acc[8];
#pragma unroll
    for (int i = 0; i < 8; ++i) acc[i] = (f4v){0.f, 0.f, 0.f, 0.f};
    for (int c = 0; c < 32; ++c) {
        int ci = 2 * c + ci0;
        const unsigned short* pa_ = Aa + ci * 81;
        const unsigned short* pb_ = Ab + ci * 81;
        s8v av, bv;
        av[0] = pa_[r0off]; av[1] = pa_[r0off + 1]; av[2] = pa_[r0off + 2]; av[3] = 0;
        av[4] = zr ? (short)0 : (short)pa_[r1off];
        av[5] = zr ? (short)0 : (short)pa_[r1off + 1];
        av[6] = zr ? (short)0 : (short)pa_[r1off + 2];
        av[7] = 0;
        bv[0] = pb_[r0off]; bv[1] = pb_[r0off + 1]; bv[2] = pb_[r0off + 2]; bv[3] = 0;
        bv[4] = zr ? (short)0 : (short)pb_[r1off];
        bv[5] = zr ? (short)0 : (short)pb_[r1off + 1];
        bv[6] = zr ? (short)0 : (short)pb_[r1off + 2];
        bv[7] = 0;
        s8v b0 = *(const s8v*)B0, b1 = *(const s8v*)B1, b2 = *(const s8v*)B2, b3 = *(const s8v*)B3;
        B0 += 32; B1 += 32; B2 += 32; B3 += 32;
        acc[0] = __builtin_amdgcn_mfma_f32_16x16x32_bf16(av, b0, acc[0], 0, 0, 0);
        acc[1] = __builtin_amdgcn_mfma_f32_16x16x32_bf16(av, b1, acc[1], 0, 0, 0);
        acc[2] = __builtin_amdgcn_mfma_f32_16x16x32_bf16(av, b2, acc[2], 0, 0, 0);
        acc[3] = __builtin_amdgcn_mfma_f32_16x16x32_bf16(av, b3, acc[3], 0, 0, 0);
        acc[4] = __builtin_amdgcn_mfma_f32_16x16x32_bf16(bv, b0, acc[4], 0, 0, 0);
        acc[5] = __builtin_amdgcn_mfma_f32_16x16x32_bf16(bv, b1, acc[5], 0, 0, 0);
        acc[6] = __builtin_amdgcn_mfma_f32_16x16x32_bf16(bv, b2, acc[6], 0, 0, 0);
        acc[7] = __builtin_amdgcn_mfma_f32_16x16x32_bf16(bv, b3, acc[7], 0, 0, 0);
    }
#pragma unroll
    for (int nf = 0; nf < 4; ++nf) {
        int n = nf * 16 + l15;
        float b = bias[n];
#pragma unroll
        for (int mf = 0; mf < 2; ++mf) {
#pragma unroll
            for (int r = 0; r < 4; ++r) {
                int ml = w * 32 + mf * 16 + q * 4 + r;
                float v = acc[mf * 4 + nf][r] + b;
                c3s[n][ml] = f2bf(v > 0.f ? v : 0.f);
            }
        }
    }
    __syncthreads();
#pragma unroll
    for (int seg = 0; seg < 32; ++seg) {
        int flat = seg * 256 + threadIdx.x;
        int n = flat >> 7, ml = flat & 127;
        int m = m0 + ml;
        int im = m / 49, p = m - im * 49;
        out[im * 3136 + n * 49 + p] = c3s[n][ml];
    }
}

// ---------------- FC (MFMA) ----------------
__global__ __launch_bounds__(256) void k_fc(const unsigned short* __restrict__ A,
                                            const unsigned short* __restrict__ Bw,
                                            const float* __restrict__ bias,
                                            unsigned short* __restrict__ out) {
    int lane = threadIdx.x & 63, w = threadIdx.x >> 6;
    int l15 = lane & 15, q = lane >> 4;
    int m0 = blockIdx.x * 32 + (w & 1) * 16;
    int n0 = blockIdx.y * 64 + (w >> 1) * 32;
    const unsigned short* Ap = A + (m0 + l15) * 3136 + q * 8;
    const unsigned short* B0 = Bw + (n0 + l15) * 3136 + q * 8;
    const unsigned short* B1 = B0 + 16 * 3136;
    f4v acc0 = (f4v){0.f, 0.f, 0.f, 0.f}, acc1 = (f4v){0.f, 0.f, 0.f, 0.f};
    for (int c = 0; c < 98; ++c) {
        s8v av = *(const s8v*)Ap;
        s8v b0 = *(const s8v*)B0;
        s8v b1 = *(const s8v*)B1;
        Ap += 32; B0 += 32; B1 += 32;
        acc0 = __builtin_amdgcn_mfma_f32_16x16x32_bf16(av, b0, acc0, 0, 0, 0);
        acc1 = __builtin_amdgcn_mfma_f32_16x16x32_bf16(av, b1, acc1, 0, 0, 0);
    }
    float bi0 = bias[n0 + l15], bi1 = bias[n0 + 16 + l15];
#pragma unroll
    for (int r = 0; r < 4; ++r) {
        int m = m0 + q * 4 + r;
        float v0 = acc0[r] + bi0; v0 = v0 > 0.f ? v0 : 0.f;
        float v1 = acc1[r] + bi1; v1 = v1 > 0.f ? v1 : 0.f;
        out[m * 512 + n0 + l15] = f2bf(v0);
        out[m * 512 + n0 + 16 + l15] = f2bf(v1);
    }
}

// ---------------- gx (MFMA) ----------------
__global__ __launch_bounds__(256) void k_gx(const unsigned short* __restrict__ A,
                                            const unsigned short* __restrict__ Bw,
                                            const float* __restrict__ Wih,
                                            const float* __restrict__ bih,
                                            const float* __restrict__ bhh,
                                            const int* __restrict__ act,
                                            float* __restrict__ out) {
    int lane = threadIdx.x & 63, w = threadIdx.x >> 6;
    int l15 = lane & 15, q = lane >> 4;
    int m0 = blockIdx.x * 32 + (w & 1) * 16;
    int n0 = blockIdx.y * 64 + (w >> 1) * 32;
    const unsigned short* Ap = A + (m0 + l15) * 512 + q * 8;
    const unsigned short* B0 = Bw + (n0 + l15) * 512 + q * 8;
    const unsigned short* B1 = B0 + 16 * 512;
    f4v acc0 = (f4v){0.f, 0.f, 0.f, 0.f}, acc1 = (f4v){0.f, 0.f, 0.f, 0.f};
    for (int c = 0; c < 16; ++c) {
        s8v av = *(const s8v*)Ap;
        s8v b0 = *(const s8v*)B0;
        s8v b1 = *(const s8v*)B1;
        Ap += 32; B0 += 32; B1 += 32;
        acc0 = __builtin_amdgcn_mfma_f32_16x16x32_bf16(av, b0, acc0, 0, 0, 0);
        acc1 = __builtin_amdgcn_mfma_f32_16x16x32_bf16(av, b1, acc1, 0, 0, 0);
    }
    int na = n0 + l15, nb = n0 + 16 + l15;
    float ca = bih[na] + bhh[na], cb_ = bih[nb] + bhh[nb];
#pragma unroll
    for (int r = 0; r < 4; ++r) {
        int m = m0 + q * 4 + r;
        int a = act[m];
        out[m * 1024 + na] = acc0[r] + Wih[na * 517 + 512 + a] + ca;
        out[m * 1024 + nb] = acc1[r] + Wih[nb * 517 + 512 + a] + cb_;
    }
}

// ---------------- fused LSTM, env-split: 32 wgs x 1 env, NO inter-wg communication ----------------
// wg owns one batch row b (independent recurrence). Wave w holds i8 Whh B-frags for n-rows
// w*64..w*64+63 (4 sets x 4 kfrags = 64 VGPR). Per step: prefetch gx (overlaps MFMA+barrier),
// h(i8, A-frag LDS, row 0 live) x Whh -> gbuf -> pointwise (256 threads) -> requantize h.
__global__ __launch_bounds__(1024) void k_lstm_all(const float* __restrict__ h0,
                                                   const float* __restrict__ c0,
                                                   const float* __restrict__ done,
                                                   const float* __restrict__ gx,
                                                   const signed char* __restrict__ Wq,
                                                   const unsigned int* __restrict__ amax_bits,
                                                   float* __restrict__ hs,
                                                   float* __restrict__ cb) {
    int b = blockIdx.x;
    int tid = threadIdx.x;
    int w = tid >> 6, lane = tid & 63;
    int l15 = lane & 15, q = lane >> 4;
    __shared__ float gbuf[1024];
    __shared__ float cst[256];
    __shared__ signed char hA[4][64][16];            // A-operand layout, only m=0 rows live

    i4v wfr[4][4];
    const signed char* wb = Wq + (w * 64 + l15) * 256 + q * 16;
#pragma unroll
    for (int s = 0; s < 4; ++s)
#pragma unroll
        for (int kf = 0; kf < 4; ++kf)
            wfr[s][kf] = *(const i4v*)(wb + s * 16 * 256 + kf * 64);
    float sw = __uint_as_float(amax_bits[0]) * (1.f / (127.f * 127.f));

    ((int*)hA)[tid] = 0;                             // zero all (dead rows stay 0)
    __syncthreads();
    if (tid < 256) {
        int u = tid;
        cst[u] = c0[b * 256 + u];
        float m0v = 1.f - done[b];
        float hv = h0[b * 256 + u] * m0v;
        hv = hv > 1.f ? 1.f : (hv < -1.f ? -1.f : hv);
        hA[u >> 6][((u >> 4) & 3) * 16][u & 15] = (signed char)(int)rintf(hv * 127.f);
    }
    __syncthreads();

    for (int t = 0; t < 32; ++t) {
        // prefetch gx for this step (consumed after the barrier -> latency hidden)
        float gxi = 0.f, gxf = 0.f, gxg = 0.f, gxo = 0.f, dcur = 0.f, dnxt = 0.f;
        if (tid < 256) {
            const float* gr = gx + (t * 32 + b) * 1024;
            gxi = gr[tid]; gxf = gr[256 + tid]; gxg = gr[512 + tid]; gxo = gr[768 + tid];
            dcur = done[t * 32 + b];
            dnxt = (t < 31) ? done[(t + 1) * 32 + b] : 1.f;
        }
        i4v acc[4];
#pragma unroll
        for (int s = 0; s < 4; ++s) acc[s] = (i4v){0, 0, 0, 0};
#pragma unroll
        for (int kf = 0; kf < 4; ++kf) {
            i4v a = *(const i4v*)&hA[kf][lane][0];
#pragma unroll
            for (int s = 0; s < 4; ++s)
                acc[s] = __builtin_amdgcn_mfma_i32_16x16x64_i8(a, wfr[s][kf], acc[s], 0, 0, 0);
        }
        if (q == 0) {                                // row 0 of C lives in reg 0 of lanes 0..15
#pragma unroll
            for (int s = 0; s < 4; ++s)
                gbuf[w * 64 + s * 16 + l15] = (float)acc[s][0];
        }
        __syncthreads();
        if (tid < 256) {
            int u = tid;
            float gi = gbuf[u] * sw + gxi;
            float gf = gbuf[256 + u] * sw + gxf;
            float gg = gbuf[512 + u] * sw + gxg;
            float go = gbuf[768 + u] * sw + gxo;
            float cm = cst[u] * (1.f - dcur);
            float cn = sigm(gf) * cm + sigm(gi) * tanhf(gg);
            float hn = sigm(go) * tanhf(cn);
            cst[u] = cn;
            hs[t * 8192 + b * 256 + u] = hn;
            float hv = hn * (1.f - dnxt);            // |h|<1; done in {0,1} -> exact
            hA[u >> 6][((u >> 4) & 3) * 16][u & 15] = (signed char)(int)rintf(hv * 127.f);
        }
        __syncthreads();
    }
    if (tid < 256) cb[b * 256 + tid] = cst[tid];
}

// ---------------- heads (fp32, unchanged) ----------------
__global__ __launch_bounds__(256) void k_heads(const float* __restrict__ hs,
                                               const float* __restrict__ cb,
                                               const float* __restrict__ Wp1, const float* __restrict__ bp1,
                                               const float* __restrict__ Wp2, const float* __restrict__ bp2,
                                               const float* __restrict__ Wv1, const float* __restrict__ bv1,
                                               const float* __restrict__ Wv2, const float* __restrict__ bv2,
                                               float* __restrict__ out) {
    int lane = threadIdx.x & 63;
    int m = blockIdx.x * 4 + (threadIdx.x >> 6);   // 0..1023
    const float4* hv = (const float4*)(hs + m * 256);
    const float4* wp = (const float4*)(Wp1 + lane * 256);
    const float4* wq = (const float4*)(Wv1 + lane * 256);
    float ap = 0.f, av = 0.f;
#pragma unroll 8
    for (int k = 0; k < 64; ++k) {
        float4 h4 = hv[k];
        float4 p4 = wp[k];
        float4 q4 = wq[k];
        ap += h4.x * p4.x + h4.y * p4.y + h4.z * p4.z + h4.w * p4.w;
        av += h4.x * q4.x + h4.y * q4.y + h4.z * q4.z + h4.w * q4.w;
    }
    float hp = tanhf(ap + bp1[lane]);
    float hq = tanhf(av + bv1[lane]);
#pragma unroll
    for (int j = 0; j < 5; ++j) {
        float s = hp * Wp2[j * 64 + lane];
        s += __shfl_xor(s, 1); s += __shfl_xor(s, 2); s += __shfl_xor(s, 4);
        s += __shfl_xor(s, 8); s += __shfl_xor(s, 16); s += __shfl_xor(s, 32);
        if (lane == 0) out[m * 5 + j] = s + bp2[j];
    }
    float s = hq * Wv2[lane];
    s += __shfl_xor(s, 1); s += __shfl_xor(s, 2); s += __shfl_xor(s, 4);
    s += __shfl_xor(s, 8); s += __shfl_xor(s, 16); s += __shfl_xor(s, 32);
    if (lane == 0) out[5120 + m] = s + bv2[0];

    int g = blockIdx.x * 256 + threadIdx.x;
    if (g < 8192) {
        out[6144 + g] = hs[31 * 8192 + g];          // hT
        out[6144 + 8192 + g] = cb[g];               // cT
    }
}

extern "C" void kernel_launch(void* const* d_in, const int* in_sizes, int n_in,
                              void* d_out, int out_size, void* d_ws, size_t ws_size,
                              hipStream_t stream) {
    const float* image = (const float*)d_in[0];
    const int*   act   = (const int*)d_in[1];
    const float* done  = (const float*)d_in[2];
    const float* h0    = (const float*)d_in[3];
    const float* c0    = (const float*)d_in[4];
    const float* W1    = (const float*)d_in[5];
    const float* b1    = (const float*)d_in[6];
    const float* W2    = (const float*)d_in[7];
    const float* b2    = (const float*)d_in[8];
    const float* W3    = (const float*)d_in[9];
    const float* b3    = (const float*)d_in[10];
    const float* Wfc   = (const float*)d_in[11];
    const float* bfc   = (const float*)d_in[12];
    const float* Wih   = (const float*)d_in[13];
    const float* Whh   = (const float*)d_in[14];
    const float* bih   = (const float*)d_in[15];
    const float* bhh   = (const float*)d_in[16];
    const float* Wp1   = (const float*)d_in[17];
    const float* bp1   = (const float*)d_in[18];
    const float* Wp2   = (const float*)d_in[19];
    const float* bp2   = (const float*)d_in[20];
    const float* Wv1   = (const float*)d_in[21];
    const float* bv1   = (const float*)d_in[22];
    const float* Wv2   = (const float*)d_in[23];
    const float* bv2   = (const float*)d_in[24];
    float* out = (float*)d_out;
    char* base = (char*)d_ws;

    // ---- workspace layout (bytes) ----
    unsigned short* a1   = (unsigned short*)(base);             // 26,214,400
    unsigned short* a2   = (unsigned short*)(base + 26214432);  // 10,616,832
    unsigned short* W2p  = (unsigned short*)(base + 36831328);
    unsigned short* W3p  = W2p + 32768;
    unsigned short* Wfcp = W2p + 98304;
    unsigned short* Wihp = W2p + 1703936;
    unsigned short* W1p  = (unsigned short*)(base + 41287776);  // 12,288
    unsigned int*   amax = (unsigned int*)(base + 41300064);    // 4 (+pad)
    signed char*    Wq   = (signed char*)(base + 41300096);     // 262,144
    unsigned short* a3   = (unsigned short*)(base);             // overlays dead a1
    unsigned short* feat = (unsigned short*)(base + 6422528);
    float* gx = (float*)(base + 7471104);
    float* hs = (float*)(base + 11665408);
    float* cb = (float*)(base + 12713984);

    hipMemsetAsync(amax, 0, 4, stream);
    k_amax<<<1024, 256, 0, stream>>>(Whh, amax);
    k_prep<<<9752, 256, 0, stream>>>(W2, W3, Wfc, Wih, W1, Whh, amax, W2p, W3p, Wfcp, Wihp, W1p, Wq);
    k_conv1<<<1600, 256, 0, stream>>>(image, W1p, b1, a1);
    k_conv2<<<648, 256, 0, stream>>>(a1, W2p, b2, a2);
    k_conv3<<<392, 256, 0, stream>>>(a2, W3p, b3, a3);
    k_fc<<<dim3(32, 8), 256, 0, stream>>>(a3, Wfcp, bfc, feat);
    k_gx<<<dim3(32, 16), 256, 0, stream>>>(feat, Wihp, Wih, bih, bhh, act, gx);
    k_lstm_all<<<32, 1024, 0, stream>>>(h0, c0, done, gx, Wq, amax, hs, cb);
    k_heads<<<256, 256, 0, stream>>>(hs, cb, Wp1, bp1, Wp2, bp2, Wv1, bv1, Wv2, bv2, out);
}